// Round 1
// baseline (435.593 us; speedup 1.0000x reference)
//
#include <hip/hip_runtime.h>
#include <hip/hip_bf16.h>

// NBFNet Bellman-Ford pass, MI355X.
// Shapes fixed by the problem: N=20000, E=200000, B=4, K=32, D=32, R=36, L=4.
#define N_NODES 20000
#define N_EDGES 200000
#define BB 4
#define KK 32
#define DD 32
#define RR 36
#define LL 4

// ---------------- ws layout (element offsets, 4B units) ----------------
constexpr size_t OFF_X0   = 0;                                        // float[B*N*D], node-major: x[(n*4+b)*32+d]
constexpr size_t OFF_X1   = OFF_X0 + (size_t)BB * N_NODES * DD;       // float[B*N*D]
constexpr size_t OFF_RP   = OFF_X1 + (size_t)BB * N_NODES * DD;       // int[N+1] row_ptr
constexpr size_t OFF_CUR  = OFF_RP + 20032;                           // int[N]  cursor / histogram
constexpr size_t OFF_ES   = OFF_CUR + N_NODES;                        // int[E]  packed src | (etype<<16)
constexpr size_t OFF_DEG  = OFF_ES + N_EDGES;                         // float[N] deg, later 1/deg
constexpr size_t OFF_SC   = OFF_DEG + N_NODES;                        // float[N] scale
constexpr size_t OFF_INV  = OFF_SC + N_NODES;                         // float[N] 1/max(scale,0.01)
constexpr size_t OFF_MEAN = OFF_INV + N_NODES;                        // float[1] mean(log(deg))
constexpr size_t OFF_REL  = OFF_MEAN + 64;                            // float[L*B*R*D] rel tables
constexpr size_t OFF_PW   = OFF_REL + (size_t)LL * BB * RR * DD;      // float[L*4*3328] prepped conv weights
constexpr size_t WS_END   = OFF_PW + (size_t)LL * 4 * 3328;           // ~22 MB total

// ---------------- prep kernels ----------------

__global__ void k_init(const int* __restrict__ h_index, const int* __restrict__ r_index,
                       const float* __restrict__ query_emb, float* __restrict__ x0,
                       int* __restrict__ cursor) {
    int i = blockIdx.x * blockDim.x + threadIdx.x;
    int stride = gridDim.x * blockDim.x;
    for (int t = i; t < N_NODES; t += stride) cursor[t] = 0;
    for (int t = i; t < BB * N_NODES * DD; t += stride) {
        int d = t & 31; int nb = t >> 5; int b = nb & 3; int n = nb >> 2;
        float v = 0.f;
        if (n == h_index[b]) v = query_emb[r_index[b] * DD + d];
        x0[t] = v;
    }
}

__global__ void k_hist(const int* __restrict__ ei, int* __restrict__ cursor) {
    int e = blockIdx.x * blockDim.x + threadIdx.x;
    if (e < N_EDGES) atomicAdd(&cursor[ei[N_EDGES + e]], 1);
}

// Single block, 1024 threads: exclusive scan of histogram -> row_ptr & cursor,
// deg (as float), and mean(log(deg)). Deterministic.
__global__ void k_scan(int* __restrict__ cursor, int* __restrict__ row_ptr,
                       float* __restrict__ degf, float* __restrict__ mean_dlog) {
    __shared__ int s_tot[1024];
    __shared__ float s_f[1024];
    const int PER = (N_NODES + 1023) / 1024;   // 20
    int tid = threadIdx.x;
    int start = tid * PER;
    int vals[20];
    int total = 0;
    #pragma unroll
    for (int j = 0; j < PER; ++j) {
        int idx = start + j;
        int v = (idx < N_NODES) ? cursor[idx] : 0;
        vals[j] = v; total += v;
    }
    s_tot[tid] = total;
    __syncthreads();
    for (int off = 1; off < 1024; off <<= 1) {
        int t = (tid >= off) ? s_tot[tid - off] : 0;
        __syncthreads();
        s_tot[tid] += t;
        __syncthreads();
    }
    int prefix = s_tot[tid] - total;   // exclusive
    float dsum = 0.f;
    int run = prefix;
    #pragma unroll
    for (int j = 0; j < PER; ++j) {
        int idx = start + j;
        if (idx < N_NODES) {
            row_ptr[idx] = run;
            cursor[idx] = run;
            int v = vals[j];
            run += v;
            float dg = (float)(v + 1);
            degf[idx] = dg;
            dsum += logf(dg);
        }
    }
    if (tid == 1023) row_ptr[N_NODES] = run;   // == E
    s_f[tid] = dsum;
    __syncthreads();
    for (int off = 512; off > 0; off >>= 1) {
        if (tid < off) s_f[tid] += s_f[tid + off];
        __syncthreads();
    }
    if (tid == 0) mean_dlog[0] = s_f[0] / (float)N_NODES;
}

__global__ void k_scatter(const int* __restrict__ ei, const int* __restrict__ et,
                          int* __restrict__ cursor, int* __restrict__ es) {
    int e = blockIdx.x * blockDim.x + threadIdx.x;
    if (e < N_EDGES) {
        int d = ei[N_EDGES + e];
        int p = atomicAdd(&cursor[d], 1);
        es[p] = ei[e] | (et[e] << 16);   // src < 2^15, type < 36
    }
}

__global__ void k_scales(float* __restrict__ degf, float* __restrict__ scale,
                         float* __restrict__ invs, const float* __restrict__ mean_dlog) {
    int n = blockIdx.x * blockDim.x + threadIdx.x;
    if (n < N_NODES) {
        float dg = degf[n];
        float sc = logf(dg) / mean_dlog[0];
        scale[n] = sc;
        invs[n] = 1.f / fmaxf(sc, 0.01f);
        degf[n] = 1.f / dg;
    }
}

__global__ void k_rel(const float* __restrict__ query_emb, const int* __restrict__ r_index,
                      const float* __restrict__ rel_W, const float* __restrict__ rel_b,
                      float* __restrict__ rel_all) {
    int i = blockIdx.x * blockDim.x + threadIdx.x;
    if (i >= LL * BB * RR * DD) return;
    int rd = i % (RR * DD);
    int lb = i / (RR * DD);
    int b = lb % BB, l = lb / BB;
    const float* q = query_emb + r_index[b] * DD;
    const float* w = rel_W + ((size_t)l * RR * DD + rd) * DD;
    float acc = rel_b[l * RR * DD + rd];
    #pragma unroll
    for (int k2 = 0; k2 < DD; ++k2) acc = fmaf(q[k2], w[k2], acc);
    rel_all[(size_t)(l * BB + b) * RR * DD + rd] = acc;
}

// Repack conv_W into per-(layer,wave) scalar-load-friendly layout:
// per (l,w): px[32][8] (x part) then pf[128][3][8] (feats part, k=1/scale/inv columns).
__global__ void k_wprep(const float* __restrict__ conv_W, float* __restrict__ pw) {
    int i = blockIdx.x * blockDim.x + threadIdx.x;
    if (i >= LL * 4 * 3328) return;
    int r = i % 3328; int lw = i / 3328;
    int w = lw & 3, l = lw >> 2;
    int o, j;
    if (r < 256) { j = r >> 3; o = r & 7; }
    else {
        int r2 = r - 256;
        int j4 = r2 / 24; int ko = r2 % 24;
        int k2 = ko >> 3; o = ko & 7;
        j = DD + j4 * 3 + k2;
    }
    pw[i] = conv_W[(size_t)(l * DD + w * 8 + o) * (13 * DD) + j];
}

// ---------------- main per-layer kernel ----------------
// Chunk = 16 nodes x 4 batches = 64 tasks.
// Phase A: 8 half-waves, lane = d. Each half-wave aggregates one node for all 4 b.
// Phase B: 4 waves, lane = task (nl*4+b). Wave w computes output dims [w*8, w*8+8).
__launch_bounds__(256, 2)
__global__ void k_layer(const float* __restrict__ xin, float* __restrict__ xout,
                        const int* __restrict__ row_ptr, const int* __restrict__ es,
                        const float* __restrict__ rel_all, const float* __restrict__ pw,
                        const float* __restrict__ rdeg, const float* __restrict__ scale,
                        const float* __restrict__ invs,
                        const int* __restrict__ h_index, const int* __restrict__ r_index,
                        const float* __restrict__ query_emb, const float* __restrict__ conv_b,
                        int l) {
    __shared__ float s_rel[BB * RR * DD];    // 18432 B
    __shared__ float s_agg[64][164];         // 41984 B; [0:32)=x, [32:160)=feats(d*4+f), [160]=scale,[161]=inv
    __shared__ float s_q[BB][DD];
    __shared__ int s_h[BB];
    int tid = threadIdx.x;
    for (int i = tid; i < BB * RR * DD; i += 256) s_rel[i] = rel_all[(size_t)l * BB * RR * DD + i];
    if (tid < BB * DD) {
        int b = tid >> 5, d = tid & 31;
        s_q[b][d] = query_emb[r_index[b] * DD + d];
    }
    if (tid < BB) s_h[tid] = h_index[tid];

    const int wv = __builtin_amdgcn_readfirstlane(tid >> 6);  // wave id, SGPR
    const int lane = tid & 63;
    const float* pwb = pw + (size_t)(l * 4 + wv) * 3328;
    float bias[8];
    #pragma unroll
    for (int oo = 0; oo < 8; ++oo) bias[oo] = conv_b[l * DD + wv * 8 + oo];

    const int hw = tid >> 5, d = tid & 31;
    const int nchunks = N_NODES / 16;   // 1250 exactly
    for (int chunk = blockIdx.x; chunk < nchunks; chunk += gridDim.x) {
        __syncthreads();   // protect s_agg from previous chunk's readers (also covers staging)
        // ---------- Phase A ----------
        #pragma unroll
        for (int pass = 0; pass < 2; ++pass) {
            int nl = pass * 8 + hw;
            int n = chunk * 16 + nl;
            float sa[4], sq[4], mx[4], mn[4], xv[4];
            #pragma unroll
            for (int b = 0; b < 4; ++b) {
                float bv = (n == s_h[b]) ? s_q[b][d] : 0.f;
                sa[b] = bv; sq[b] = bv * bv; mx[b] = bv; mn[b] = bv;
                xv[b] = xin[(size_t)(n * 4 + b) * DD + d];
            }
            int e0 = row_ptr[n], e1 = row_ptr[n + 1];
            int e = e0;
            for (; e + 1 < e1; e += 2) {   // 2-edge unroll: 2x memory-level parallelism
                int pka = es[e], pkb = es[e + 1];
                const float* xra = xin + (size_t)(pka & 0xFFFF) * 128 + d;
                const float* rra = s_rel + (pka >> 16) * DD + d;
                const float* xrb = xin + (size_t)(pkb & 0xFFFF) * 128 + d;
                const float* rrb = s_rel + (pkb >> 16) * DD + d;
                #pragma unroll
                for (int b = 0; b < 4; ++b) {
                    float ma = xra[b * 32] * rra[b * RR * DD];
                    float mb = xrb[b * 32] * rrb[b * RR * DD];
                    sa[b] += ma; sq[b] = fmaf(ma, ma, sq[b]);
                    mx[b] = fmaxf(mx[b], ma); mn[b] = fminf(mn[b], ma);
                    sa[b] += mb; sq[b] = fmaf(mb, mb, sq[b]);
                    mx[b] = fmaxf(mx[b], mb); mn[b] = fminf(mn[b], mb);
                }
            }
            if (e < e1) {
                int pk = es[e];
                const float* xr = xin + (size_t)(pk & 0xFFFF) * 128 + d;
                const float* rr = s_rel + (pk >> 16) * DD + d;
                #pragma unroll
                for (int b = 0; b < 4; ++b) {
                    float m = xr[b * 32] * rr[b * RR * DD];
                    sa[b] += m; sq[b] = fmaf(m, m, sq[b]);
                    mx[b] = fmaxf(mx[b], m); mn[b] = fminf(mn[b], m);
                }
            }
            float rd_ = rdeg[n];
            float scn = scale[n], ivn = invs[n];
            #pragma unroll
            for (int b = 0; b < 4; ++b) {
                float mean = sa[b] * rd_;
                float sqm = sq[b] * rd_;
                float sd = sqrtf(fmaxf(sqm - mean * mean, 1e-6f));
                int t_l = nl * 4 + b;
                s_agg[t_l][d] = xv[b];
                float4 f4 = make_float4(mean, mx[b], mn[b], sd);
                *(float4*)&s_agg[t_l][DD + d * 4] = f4;
            }
            if (d < 4) {
                s_agg[nl * 4 + d][160] = scn;
                s_agg[nl * 4 + d][161] = ivn;
            }
        }
        __syncthreads();
        // ---------- Phase B: conv ----------
        {
            int nl = lane >> 2, b = lane & 3;
            int n = chunk * 16 + nl;
            float y0[8], y1[8], y2[8];
            #pragma unroll
            for (int oo = 0; oo < 8; ++oo) { y0[oo] = bias[oo]; y1[oo] = 0.f; y2[oo] = 0.f; }
            const float* arow = &s_agg[lane][0];
            #pragma unroll
            for (int j0 = 0; j0 < 32; j0 += 4) {
                float4 c = *(const float4*)&arow[j0];
                #pragma unroll
                for (int jj = 0; jj < 4; ++jj) {
                    const float* pp = pwb + (j0 + jj) * 8;
                    float cv = (&c.x)[jj];
                    #pragma unroll
                    for (int oo = 0; oo < 8; ++oo) y0[oo] = fmaf(cv, pp[oo], y0[oo]);
                }
            }
            const float* pf = pwb + 256;
            #pragma unroll 2
            for (int j40 = 0; j40 < 128; j40 += 4) {
                float4 c = *(const float4*)&arow[DD + j40];
                #pragma unroll
                for (int jj = 0; jj < 4; ++jj) {
                    const float* pp = pf + (j40 + jj) * 24;
                    float cv = (&c.x)[jj];
                    #pragma unroll
                    for (int oo = 0; oo < 8; ++oo) {
                        y0[oo] = fmaf(cv, pp[oo], y0[oo]);
                        y1[oo] = fmaf(cv, pp[8 + oo], y1[oo]);
                        y2[oo] = fmaf(cv, pp[16 + oo], y2[oo]);
                    }
                }
            }
            float scn = arow[160], ivn = arow[161];
            float* xo = xout + (size_t)(n * 4 + b) * DD + wv * 8;
            float4 o0, o1;
            o0.x = fmaxf(0.f, y0[0] + scn * y1[0] + ivn * y2[0]);
            o0.y = fmaxf(0.f, y0[1] + scn * y1[1] + ivn * y2[1]);
            o0.z = fmaxf(0.f, y0[2] + scn * y1[2] + ivn * y2[2]);
            o0.w = fmaxf(0.f, y0[3] + scn * y1[3] + ivn * y2[3]);
            o1.x = fmaxf(0.f, y0[4] + scn * y1[4] + ivn * y2[4]);
            o1.y = fmaxf(0.f, y0[5] + scn * y1[5] + ivn * y2[5]);
            o1.z = fmaxf(0.f, y0[6] + scn * y1[6] + ivn * y2[6]);
            o1.w = fmaxf(0.f, y0[7] + scn * y1[7] + ivn * y2[7]);
            *(float4*)&xo[0] = o0;
            *(float4*)&xo[4] = o1;
        }
    }
}

// ---------------- final scoring ----------------
__global__ void k_score(const float* __restrict__ xL, const float* __restrict__ query_emb,
                        const int* __restrict__ r_index, const int* __restrict__ t_index,
                        const float* __restrict__ W1, const float* __restrict__ b1,
                        const float* __restrict__ W2, const float* __restrict__ b2,
                        float* __restrict__ out) {
    int bi = blockIdx.x;            // 0..127
    int b = bi >> 5, kk = bi & 31;
    int j = threadIdx.x;            // 0..63
    __shared__ float sf[64];
    int t = t_index[b * KK + kk];
    float f = (j < DD) ? xL[(size_t)(t * 4 + b) * DD + j]
                       : query_emb[r_index[b] * DD + (j - DD)];
    sf[j] = f;
    __syncthreads();
    float acc = b1[j];
    #pragma unroll 8
    for (int i2 = 0; i2 < 64; ++i2) acc = fmaf(sf[i2], W1[j * 64 + i2], acc);
    float h = fmaxf(acc, 0.f);
    float prod = h * W2[j];
    #pragma unroll
    for (int off = 32; off > 0; off >>= 1) prod += __shfl_down(prod, off);
    if (j == 0) out[b * KK + kk] = prod + b2[0];
}

extern "C" void kernel_launch(void* const* d_in, const int* in_sizes, int n_in,
                              void* d_out, int out_size, void* d_ws, size_t ws_size,
                              hipStream_t stream) {
    const int* ei        = (const int*)d_in[0];
    const int* et        = (const int*)d_in[1];
    const int* h_index   = (const int*)d_in[2];
    const int* t_index   = (const int*)d_in[3];
    const int* r_index   = (const int*)d_in[4];
    const float* query_emb = (const float*)d_in[6];
    const float* rel_W   = (const float*)d_in[7];
    const float* rel_b   = (const float*)d_in[8];
    const float* conv_W  = (const float*)d_in[9];
    const float* conv_b  = (const float*)d_in[10];
    const float* W1      = (const float*)d_in[11];
    const float* b1      = (const float*)d_in[12];
    const float* W2      = (const float*)d_in[13];
    const float* b2      = (const float*)d_in[14];

    float* ws = (float*)d_ws;
    float* x0      = ws + OFF_X0;
    float* x1      = ws + OFF_X1;
    int*   row_ptr = (int*)(ws + OFF_RP);
    int*   cursor  = (int*)(ws + OFF_CUR);
    int*   es      = (int*)(ws + OFF_ES);
    float* degf    = ws + OFF_DEG;   // deg, then 1/deg after k_scales
    float* sc      = ws + OFF_SC;
    float* invs    = ws + OFF_INV;
    float* meanw   = ws + OFF_MEAN;
    float* rel_all = ws + OFF_REL;
    float* pw      = ws + OFF_PW;
    float* out     = (float*)d_out;

    // prep
    k_init<<<1024, 256, 0, stream>>>(h_index, r_index, query_emb, x0, cursor);
    k_hist<<<(N_EDGES + 255) / 256, 256, 0, stream>>>(ei, cursor);
    k_scan<<<1, 1024, 0, stream>>>(cursor, row_ptr, degf, meanw);
    k_scatter<<<(N_EDGES + 255) / 256, 256, 0, stream>>>(ei, et, cursor, es);
    k_scales<<<(N_NODES + 255) / 256, 256, 0, stream>>>(degf, sc, invs, meanw);
    k_rel<<<(LL * BB * RR * DD + 255) / 256, 256, 0, stream>>>(query_emb, r_index, rel_W, rel_b, rel_all);
    k_wprep<<<(LL * 4 * 3328 + 255) / 256, 256, 0, stream>>>(conv_W, pw);

    // 4 BF layers, ping-pong x0/x1: 0->1->0->1->0
    k_layer<<<512, 256, 0, stream>>>(x0, x1, row_ptr, es, rel_all, pw, degf, sc, invs,
                                     h_index, r_index, query_emb, conv_b, 0);
    k_layer<<<512, 256, 0, stream>>>(x1, x0, row_ptr, es, rel_all, pw, degf, sc, invs,
                                     h_index, r_index, query_emb, conv_b, 1);
    k_layer<<<512, 256, 0, stream>>>(x0, x1, row_ptr, es, rel_all, pw, degf, sc, invs,
                                     h_index, r_index, query_emb, conv_b, 2);
    k_layer<<<512, 256, 0, stream>>>(x1, x0, row_ptr, es, rel_all, pw, degf, sc, invs,
                                     h_index, r_index, query_emb, conv_b, 3);

    k_score<<<BB * KK, 64, 0, stream>>>(x0, query_emb, r_index, t_index, W1, b1, W2, b2, out);
}

// Round 2
// 427.951 us; speedup vs baseline: 1.0179x; 1.0179x over previous
//
#include <hip/hip_runtime.h>
#include <hip/hip_bf16.h>

// NBFNet Bellman-Ford pass, MI355X. N=20000, E=200000, B=4, K=32, D=32, R=36, L=4.
#define N_NODES 20000
#define N_EDGES 200000
#define BB 4
#define KK 32
#define DD 32
#define RR 36
#define LL 4
#define NCHUNKS (N_NODES / 16)

// ---------------- ws layout (element offsets, 4B units) ----------------
constexpr size_t OFF_X0   = 0;                                        // float[B*N*D], x[(n*4+b)*32+d]
constexpr size_t OFF_X1   = OFF_X0 + (size_t)BB * N_NODES * DD;
constexpr size_t OFF_RP   = OFF_X1 + (size_t)BB * N_NODES * DD;       // int[N+1]
constexpr size_t OFF_CUR  = OFF_RP + 20032;                           // int[N]
constexpr size_t OFF_ES   = OFF_CUR + N_NODES;                        // int[E] src | type<<16
constexpr size_t OFF_DEG  = OFF_ES + N_EDGES;                         // float[N] 1/deg
constexpr size_t OFF_SC   = OFF_DEG + N_NODES;                        // float[N] scale
constexpr size_t OFF_INV  = OFF_SC + N_NODES;                         // float[N] 1/max(scale,.01)
constexpr size_t OFF_CTR  = OFF_INV + N_NODES;                        // int[16] work counters
constexpr size_t OFF_REL  = OFF_CTR + 16;                             // float[L*R*B*D] [l][ty][b][d]
constexpr size_t OFF_PW   = OFF_REL + (size_t)LL * RR * BB * DD;      // float[L*4*3328]

// ---------------- prep kernels ----------------

__global__ void k_init(const int* __restrict__ h_index, const int* __restrict__ r_index,
                       const float* __restrict__ query_emb, float* __restrict__ x0,
                       int* __restrict__ cursor, int* __restrict__ ctr) {
    int i = blockIdx.x * blockDim.x + threadIdx.x;
    if (i < 16) ctr[i] = 0;
    int stride = gridDim.x * blockDim.x;
    for (int t = i; t < N_NODES; t += stride) cursor[t] = 0;
    for (int t = i; t < BB * N_NODES * DD; t += stride) {
        int d = t & 31; int nb = t >> 5; int b = nb & 3; int n = nb >> 2;
        float v = 0.f;
        if (n == h_index[b]) v = query_emb[r_index[b] * DD + d];
        x0[t] = v;
    }
}

__global__ void k_hist(const int* __restrict__ ei, int* __restrict__ cursor) {
    int e = blockIdx.x * blockDim.x + threadIdx.x;
    if (e < N_EDGES) atomicAdd(&cursor[ei[N_EDGES + e]], 1);
}

// Single block: scan histogram -> row_ptr/cursor, plus rdeg/scale/inv (deterministic).
__global__ void k_scan(int* __restrict__ cursor, int* __restrict__ row_ptr,
                       float* __restrict__ rdeg, float* __restrict__ scale,
                       float* __restrict__ invs) {
    __shared__ int s_tot[1024];
    __shared__ float s_f[1024];
    const int PER = (N_NODES + 1023) / 1024;   // 20
    int tid = threadIdx.x;
    int start = tid * PER;
    int vals[20];
    float dls[20];
    int total = 0;
    #pragma unroll
    for (int j = 0; j < PER; ++j) {
        int idx = start + j;
        int v = (idx < N_NODES) ? cursor[idx] : 0;
        vals[j] = v; total += v;
    }
    s_tot[tid] = total;
    __syncthreads();
    for (int off = 1; off < 1024; off <<= 1) {
        int t = (tid >= off) ? s_tot[tid - off] : 0;
        __syncthreads();
        s_tot[tid] += t;
        __syncthreads();
    }
    int prefix = s_tot[tid] - total;   // exclusive
    float dsum = 0.f;
    int run = prefix;
    #pragma unroll
    for (int j = 0; j < PER; ++j) {
        int idx = start + j;
        if (idx < N_NODES) {
            row_ptr[idx] = run;
            cursor[idx] = run;
            run += vals[j];
            float lg = logf((float)(vals[j] + 1));
            dls[j] = lg;
            dsum += lg;
        }
    }
    if (tid == 1023) row_ptr[N_NODES] = run;
    s_f[tid] = dsum;
    __syncthreads();
    for (int off = 512; off > 0; off >>= 1) {
        if (tid < off) s_f[tid] += s_f[tid + off];
        __syncthreads();
    }
    float mean = s_f[0] / (float)N_NODES;
    #pragma unroll
    for (int j = 0; j < PER; ++j) {
        int idx = start + j;
        if (idx < N_NODES) {
            float dg = (float)(vals[j] + 1);
            float sc = dls[j] / mean;
            rdeg[idx] = 1.f / dg;
            scale[idx] = sc;
            invs[idx] = 1.f / fmaxf(sc, 0.01f);
        }
    }
}

__global__ void k_scatter(const int* __restrict__ ei, const int* __restrict__ et,
                          int* __restrict__ cursor, int* __restrict__ es) {
    int e = blockIdx.x * blockDim.x + threadIdx.x;
    if (e < N_EDGES) {
        int dnode = ei[N_EDGES + e];
        int p = atomicAdd(&cursor[dnode], 1);
        es[p] = ei[e] | (et[e] << 16);
    }
}

// rel tables [l][type][b][d] (512B per type-block, L1-friendly) + prepped conv weights.
__global__ void k_prep_w(const float* __restrict__ query_emb, const int* __restrict__ r_index,
                         const float* __restrict__ rel_W, const float* __restrict__ rel_b,
                         const float* __restrict__ conv_W,
                         float* __restrict__ rel_all, float* __restrict__ pw) {
    int i = blockIdx.x * blockDim.x + threadIdx.x;
    const int NREL = LL * BB * RR * DD;
    if (i < NREL) {
        int d = i & 31;
        int ty = (i >> 5) % RR;
        int b = (i / (32 * RR)) & 3;
        int l = i / (32 * RR * BB);
        const float* q = query_emb + r_index[b] * DD;
        const float* w = rel_W + ((size_t)l * RR * DD + ty * DD + d) * DD;
        float acc = rel_b[l * RR * DD + ty * DD + d];
        #pragma unroll
        for (int k2 = 0; k2 < DD; ++k2) acc = fmaf(q[k2], w[k2], acc);
        rel_all[(((size_t)l * RR + ty) * BB + b) * DD + d] = acc;
    } else {
        int i2 = i - NREL;
        if (i2 >= LL * 4 * 3328) return;
        int r = i2 % 3328; int lw = i2 / 3328;
        int w = lw & 3, l = lw >> 2;
        int o, j;
        if (r < 256) { j = r >> 3; o = r & 7; }
        else {
            int r2 = r - 256;
            int j4 = r2 / 24; int ko = r2 % 24;
            int k2 = ko >> 3; o = ko & 7;
            j = DD + j4 * 3 + k2;
        }
        pw[i2] = conv_W[(size_t)(l * DD + w * 8 + o) * (13 * DD) + j];
    }
}

// ---------------- main per-layer kernel ----------------
// Chunk = 16 nodes x 4 batches. Dynamic chunk queue (global atomic).
// Phase A: wave-per-node (4 nodes/wave), lane = d + 32*edge_parity; combine via shfl_xor(32).
// Phase B: lane = task (nl*4+b), wave wv computes output dims [wv*8, wv*8+8).
// s_agg[64][128] XOR-swizzled (j ^= (t&7)<<2) -> conflict-free b128 LDS.
__launch_bounds__(256, 4)
__global__ void k_layer(const float* __restrict__ xin, float* __restrict__ xout,
                        const int* __restrict__ row_ptr, const int* __restrict__ es,
                        const float* __restrict__ rel_l, const float* __restrict__ pw_l,
                        const float* __restrict__ rdeg, const float* __restrict__ scale,
                        const float* __restrict__ invs,
                        const int* __restrict__ h_index, const int* __restrict__ r_index,
                        const float* __restrict__ query_emb, const float* __restrict__ conv_b_l,
                        int* __restrict__ ctr) {
    __shared__ __align__(16) float s_agg[64 * 128];   // 32 KB
    __shared__ float s_sc[64], s_iv[64];
    __shared__ float s_q[BB][DD];
    __shared__ int s_h[BB];
    __shared__ int s_chunk;
    const int tid = threadIdx.x;
    if (tid < BB * DD) {
        int b = tid >> 5, dd = tid & 31;
        s_q[b][dd] = query_emb[r_index[b] * DD + dd];
    }
    if (tid < BB) s_h[tid] = h_index[tid];

    const int wv = __builtin_amdgcn_readfirstlane(tid >> 6);
    const int lane = tid & 63;
    const int d = lane & 31;
    const int par = lane >> 5;
    const float* pwb = pw_l + wv * 3328;
    float bias[8];
    #pragma unroll
    for (int oo = 0; oo < 8; ++oo) bias[oo] = conv_b_l[wv * 8 + oo];

    while (true) {
        __syncthreads();   // previous chunk's Phase B done before s_agg/s_chunk reuse
        if (tid == 0) s_chunk = atomicAdd(ctr, 1);
        __syncthreads();
        const int chunk = s_chunk;
        if (chunk >= NCHUNKS) break;

        // ---------- Phase A ----------
        #pragma unroll 1
        for (int i4 = 0; i4 < 4; ++i4) {
            const int nl = wv * 4 + i4;
            const int n = chunk * 16 + nl;
            float sa[4], sq[4], mx[4], mn[4];
            #pragma unroll
            for (int b = 0; b < 4; ++b) {
                float bv = (n == s_h[b]) ? s_q[b][d] : 0.f;
                float bs = par ? 0.f : bv;      // count boundary once in sum/sq
                sa[b] = bs; sq[b] = bs * bv; mx[b] = bv; mn[b] = bv;
            }
            auto proc = [&](int ee) {
                int pk = es[ee];
                const float* xr = xin + (size_t)(pk & 0xFFFF) * 128 + d;
                const float* rr = rel_l + (pk >> 16) * (BB * DD) + d;
                #pragma unroll
                for (int b = 0; b < 4; ++b) {
                    float m = xr[b * 32] * rr[b * 32];
                    sa[b] += m; sq[b] = fmaf(m, m, sq[b]);
                    mx[b] = fmaxf(mx[b], m); mn[b] = fminf(mn[b], m);
                }
            };
            int e0 = row_ptr[n], e1 = row_ptr[n + 1];
            int e = e0 + par;                    // parity-strided: 2 edges/wave-iter
            for (; e + 2 < e1; e += 4) { proc(e); proc(e + 2); }   // 4 edges in flight
            for (; e < e1; e += 2) proc(e);
            // combine halves
            #pragma unroll
            for (int b = 0; b < 4; ++b) {
                sa[b] += __shfl_xor(sa[b], 32);
                sq[b] += __shfl_xor(sq[b], 32);
                mx[b] = fmaxf(mx[b], __shfl_xor(mx[b], 32));
                mn[b] = fminf(mn[b], __shfl_xor(mn[b], 32));
            }
            float rd_ = rdeg[n];
            float mean[4], sd[4];
            #pragma unroll
            for (int b = 0; b < 4; ++b) {
                mean[b] = sa[b] * rd_;
                float sm = sq[b] * rd_;
                sd[b] = sqrtf(fmaxf(sm - mean[b] * mean[b], 1e-6f));
            }
            // each half writes 2 tasks (b = par*2, par*2+1); constant reg indices + cndmask
            int tA = nl * 4 + par * 2;
            int tB2 = tA + 1;
            float4 fA, fB;
            fA.x = par ? mean[2] : mean[0]; fA.y = par ? mx[2] : mx[0];
            fA.z = par ? mn[2] : mn[0];     fA.w = par ? sd[2] : sd[0];
            fB.x = par ? mean[3] : mean[1]; fB.y = par ? mx[3] : mx[1];
            fB.z = par ? mn[3] : mn[1];     fB.w = par ? sd[3] : sd[1];
            *(float4*)&s_agg[tA * 128 + ((4 * d) ^ ((tA & 7) << 2))] = fA;
            *(float4*)&s_agg[tB2 * 128 + ((4 * d) ^ ((tB2 & 7) << 2))] = fB;
            float scn = scale[n], ivn = invs[n];
            if (lane < 4) { s_sc[nl * 4 + lane] = scn; s_iv[nl * 4 + lane] = ivn; }
        }
        __syncthreads();
        // ---------- Phase B: conv ----------
        {
            const int t = lane;
            const int nl2 = t >> 2, b2 = t & 3;
            const int n2 = chunk * 16 + nl2;
            float y0[8], y1[8], y2[8];
            #pragma unroll
            for (int oo = 0; oo < 8; ++oo) { y0[oo] = bias[oo]; y1[oo] = 0.f; y2[oo] = 0.f; }
            // x part from global (L1-hot)
            const float* xg = xin + (size_t)(n2 * 4 + b2) * DD;
            #pragma unroll
            for (int j0 = 0; j0 < 32; j0 += 4) {
                float4 c = *(const float4*)(xg + j0);
                #pragma unroll
                for (int jj = 0; jj < 4; ++jj) {
                    const float* pp = pwb + (j0 + jj) * 8;
                    float cv = (&c.x)[jj];
                    #pragma unroll
                    for (int oo = 0; oo < 8; ++oo) y0[oo] = fmaf(cv, pp[oo], y0[oo]);
                }
            }
            // feats from swizzled LDS
            const float* pf = pwb + 256;
            const float* arow = s_agg + t * 128;
            const int sw = (t & 7) << 2;
            #pragma unroll 2
            for (int j40 = 0; j40 < 128; j40 += 4) {
                float4 c = *(const float4*)(arow + (j40 ^ sw));
                #pragma unroll
                for (int jj = 0; jj < 4; ++jj) {
                    const float* pp = pf + (j40 + jj) * 24;
                    float cv = (&c.x)[jj];
                    #pragma unroll
                    for (int oo = 0; oo < 8; ++oo) {
                        y0[oo] = fmaf(cv, pp[oo], y0[oo]);
                        y1[oo] = fmaf(cv, pp[8 + oo], y1[oo]);
                        y2[oo] = fmaf(cv, pp[16 + oo], y2[oo]);
                    }
                }
            }
            float scn = s_sc[t], ivn = s_iv[t];
            float* xo = xout + (size_t)(n2 * 4 + b2) * DD + wv * 8;
            float4 o0, o1;
            o0.x = fmaxf(0.f, y0[0] + scn * y1[0] + ivn * y2[0]);
            o0.y = fmaxf(0.f, y0[1] + scn * y1[1] + ivn * y2[1]);
            o0.z = fmaxf(0.f, y0[2] + scn * y1[2] + ivn * y2[2]);
            o0.w = fmaxf(0.f, y0[3] + scn * y1[3] + ivn * y2[3]);
            o1.x = fmaxf(0.f, y0[4] + scn * y1[4] + ivn * y2[4]);
            o1.y = fmaxf(0.f, y0[5] + scn * y1[5] + ivn * y2[5]);
            o1.z = fmaxf(0.f, y0[6] + scn * y1[6] + ivn * y2[6]);
            o1.w = fmaxf(0.f, y0[7] + scn * y1[7] + ivn * y2[7]);
            *(float4*)&xo[0] = o0;
            *(float4*)&xo[4] = o1;
        }
    }
}

// ---------------- final scoring ----------------
__global__ void k_score(const float* __restrict__ xL, const float* __restrict__ query_emb,
                        const int* __restrict__ r_index, const int* __restrict__ t_index,
                        const float* __restrict__ W1, const float* __restrict__ b1,
                        const float* __restrict__ W2, const float* __restrict__ b2,
                        float* __restrict__ out) {
    int bi = blockIdx.x;            // 0..127
    int b = bi >> 5, kk = bi & 31;
    int j = threadIdx.x;            // 0..63
    __shared__ float sf[64];
    int t = t_index[b * KK + kk];
    float f = (j < DD) ? xL[(size_t)(t * 4 + b) * DD + j]
                       : query_emb[r_index[b] * DD + (j - DD)];
    sf[j] = f;
    __syncthreads();
    float acc = b1[j];
    #pragma unroll 8
    for (int i2 = 0; i2 < 64; ++i2) acc = fmaf(sf[i2], W1[j * 64 + i2], acc);
    float h = fmaxf(acc, 0.f);
    float prod = h * W2[j];
    #pragma unroll
    for (int off = 32; off > 0; off >>= 1) prod += __shfl_down(prod, off);
    if (j == 0) out[b * KK + kk] = prod + b2[0];
}

extern "C" void kernel_launch(void* const* d_in, const int* in_sizes, int n_in,
                              void* d_out, int out_size, void* d_ws, size_t ws_size,
                              hipStream_t stream) {
    const int* ei        = (const int*)d_in[0];
    const int* et        = (const int*)d_in[1];
    const int* h_index   = (const int*)d_in[2];
    const int* t_index   = (const int*)d_in[3];
    const int* r_index   = (const int*)d_in[4];
    const float* query_emb = (const float*)d_in[6];
    const float* rel_W   = (const float*)d_in[7];
    const float* rel_b   = (const float*)d_in[8];
    const float* conv_W  = (const float*)d_in[9];
    const float* conv_b  = (const float*)d_in[10];
    const float* W1      = (const float*)d_in[11];
    const float* b1      = (const float*)d_in[12];
    const float* W2      = (const float*)d_in[13];
    const float* b2      = (const float*)d_in[14];

    float* ws = (float*)d_ws;
    float* x0      = ws + OFF_X0;
    float* x1      = ws + OFF_X1;
    int*   row_ptr = (int*)(ws + OFF_RP);
    int*   cursor  = (int*)(ws + OFF_CUR);
    int*   es      = (int*)(ws + OFF_ES);
    float* rdeg    = ws + OFF_DEG;
    float* sc      = ws + OFF_SC;
    float* invs    = ws + OFF_INV;
    int*   ctr     = (int*)(ws + OFF_CTR);
    float* rel_all = ws + OFF_REL;
    float* pw      = ws + OFF_PW;
    float* out     = (float*)d_out;

    // prep
    k_init<<<1024, 256, 0, stream>>>(h_index, r_index, query_emb, x0, cursor, ctr);
    k_hist<<<(N_EDGES + 255) / 256, 256, 0, stream>>>(ei, cursor);
    k_scan<<<1, 1024, 0, stream>>>(cursor, row_ptr, rdeg, sc, invs);
    k_scatter<<<(N_EDGES + 255) / 256, 256, 0, stream>>>(ei, et, cursor, es);
    const int NPREP = LL * BB * RR * DD + LL * 4 * 3328;
    k_prep_w<<<(NPREP + 255) / 256, 256, 0, stream>>>(query_emb, r_index, rel_W, rel_b,
                                                      conv_W, rel_all, pw);

    // 4 BF layers, ping-pong x0/x1
    for (int l = 0; l < LL; ++l) {
        const float* xi = (l & 1) ? x1 : x0;
        float* xo = (l & 1) ? x0 : x1;
        k_layer<<<1024, 256, 0, stream>>>(xi, xo, row_ptr, es,
                                          rel_all + (size_t)l * RR * BB * DD,
                                          pw + (size_t)l * 4 * 3328,
                                          rdeg, sc, invs, h_index, r_index, query_emb,
                                          conv_b + l * DD, ctr + l);
    }

    k_score<<<BB * KK, 64, 0, stream>>>(x0, query_emb, r_index, t_index, W1, b1, W2, b2, out);
}

// Round 3
// 416.758 us; speedup vs baseline: 1.0452x; 1.0269x over previous
//
#include <hip/hip_runtime.h>
#include <hip/hip_bf16.h>

// NBFNet Bellman-Ford pass, MI355X. N=20000, E=200000, B=4, K=32, D=32, R=36, L=4.
#define N_NODES 20000
#define N_EDGES 200000
#define BB 4
#define KK 32
#define DD 32
#define RR 36
#define LL 4
#define NCHUNKS (N_NODES / 16)

// ---------------- ws layout (element offsets, 4B units) ----------------
constexpr size_t OFF_X0   = 0;                                        // float[B*N*D], x[(n*4+b)*32+d]
constexpr size_t OFF_X1   = OFF_X0 + (size_t)BB * N_NODES * DD;
constexpr size_t OFF_RP   = OFF_X1 + (size_t)BB * N_NODES * DD;       // int[N+1]
constexpr size_t OFF_CUR  = OFF_RP + 20032;                           // int[N]
constexpr size_t OFF_ES   = OFF_CUR + N_NODES;                        // int[E] src | type<<16
constexpr size_t OFF_DEG  = OFF_ES + N_EDGES;                         // float[N] 1/deg
constexpr size_t OFF_SC   = OFF_DEG + N_NODES;                        // float[N] scale
constexpr size_t OFF_INV  = OFF_SC + N_NODES;                         // float[N] 1/max(scale,.01)
constexpr size_t OFF_CTR  = OFF_INV + N_NODES;                        // int[16] work counters
constexpr size_t OFF_REL  = OFF_CTR + 16;                             // float[L*R*B*D] [l][ty][b][d]
constexpr size_t OFF_PW   = OFF_REL + (size_t)LL * RR * BB * DD;      // float[L*4*3328] (16B aligned)

// ---------------- prep kernels ----------------

__global__ void k_init(const int* __restrict__ h_index, const int* __restrict__ r_index,
                       const float* __restrict__ query_emb, float* __restrict__ x0,
                       int* __restrict__ cursor, int* __restrict__ ctr) {
    int i = blockIdx.x * blockDim.x + threadIdx.x;
    if (i < 16) ctr[i] = 0;
    int stride = gridDim.x * blockDim.x;
    for (int t = i; t < N_NODES; t += stride) cursor[t] = 0;
    for (int t = i; t < BB * N_NODES * DD; t += stride) {
        int d = t & 31; int nb = t >> 5; int b = nb & 3; int n = nb >> 2;
        float v = 0.f;
        if (n == h_index[b]) v = query_emb[r_index[b] * DD + d];
        x0[t] = v;
    }
}

__global__ void k_hist(const int* __restrict__ ei, int* __restrict__ cursor) {
    int e = blockIdx.x * blockDim.x + threadIdx.x;
    if (e < N_EDGES) atomicAdd(&cursor[ei[N_EDGES + e]], 1);
}

// Single block: scan histogram -> row_ptr/cursor, plus rdeg/scale/inv (deterministic).
__global__ void k_scan(int* __restrict__ cursor, int* __restrict__ row_ptr,
                       float* __restrict__ rdeg, float* __restrict__ scale,
                       float* __restrict__ invs) {
    __shared__ int s_tot[1024];
    __shared__ float s_f[1024];
    const int PER = (N_NODES + 1023) / 1024;   // 20
    int tid = threadIdx.x;
    int start = tid * PER;
    int vals[20];
    float dls[20];
    int total = 0;
    #pragma unroll
    for (int j = 0; j < PER; ++j) {
        int idx = start + j;
        int v = (idx < N_NODES) ? cursor[idx] : 0;
        vals[j] = v; total += v;
    }
    s_tot[tid] = total;
    __syncthreads();
    for (int off = 1; off < 1024; off <<= 1) {
        int t = (tid >= off) ? s_tot[tid - off] : 0;
        __syncthreads();
        s_tot[tid] += t;
        __syncthreads();
    }
    int prefix = s_tot[tid] - total;   // exclusive
    float dsum = 0.f;
    int run = prefix;
    #pragma unroll
    for (int j = 0; j < PER; ++j) {
        int idx = start + j;
        if (idx < N_NODES) {
            row_ptr[idx] = run;
            cursor[idx] = run;
            run += vals[j];
            float lg = logf((float)(vals[j] + 1));
            dls[j] = lg;
            dsum += lg;
        }
    }
    if (tid == 1023) row_ptr[N_NODES] = run;
    s_f[tid] = dsum;
    __syncthreads();
    for (int off = 512; off > 0; off >>= 1) {
        if (tid < off) s_f[tid] += s_f[tid + off];
        __syncthreads();
    }
    float mean = s_f[0] / (float)N_NODES;
    #pragma unroll
    for (int j = 0; j < PER; ++j) {
        int idx = start + j;
        if (idx < N_NODES) {
            float dg = (float)(vals[j] + 1);
            float sc = dls[j] / mean;
            rdeg[idx] = 1.f / dg;
            scale[idx] = sc;
            invs[idx] = 1.f / fmaxf(sc, 0.01f);
        }
    }
}

__global__ void k_scatter(const int* __restrict__ ei, const int* __restrict__ et,
                          int* __restrict__ cursor, int* __restrict__ es) {
    int e = blockIdx.x * blockDim.x + threadIdx.x;
    if (e < N_EDGES) {
        int dnode = ei[N_EDGES + e];
        int p = atomicAdd(&cursor[dnode], 1);
        es[p] = ei[e] | (et[e] << 16);
    }
}

// rel tables [l][type][b][d] (512B per type-block, L1-friendly) + prepped conv weights.
__global__ void k_prep_w(const float* __restrict__ query_emb, const int* __restrict__ r_index,
                         const float* __restrict__ rel_W, const float* __restrict__ rel_b,
                         const float* __restrict__ conv_W,
                         float* __restrict__ rel_all, float* __restrict__ pw) {
    int i = blockIdx.x * blockDim.x + threadIdx.x;
    const int NREL = LL * BB * RR * DD;
    if (i < NREL) {
        int d = i & 31;
        int ty = (i >> 5) % RR;
        int b = (i / (32 * RR)) & 3;
        int l = i / (32 * RR * BB);
        const float* q = query_emb + r_index[b] * DD;
        const float* w = rel_W + ((size_t)l * RR * DD + ty * DD + d) * DD;
        float acc = rel_b[l * RR * DD + ty * DD + d];
        #pragma unroll
        for (int k2 = 0; k2 < DD; ++k2) acc = fmaf(q[k2], w[k2], acc);
        rel_all[(((size_t)l * RR + ty) * BB + b) * DD + d] = acc;
    } else {
        int i2 = i - NREL;
        if (i2 >= LL * 4 * 3328) return;
        int r = i2 % 3328; int lw = i2 / 3328;
        int w = lw & 3, l = lw >> 2;
        int o, j;
        if (r < 256) { j = r >> 3; o = r & 7; }
        else {
            int r2 = r - 256;
            int j4 = r2 / 24; int ko = r2 % 24;
            int k2 = ko >> 3; o = ko & 7;
            j = DD + j4 * 3 + k2;
        }
        pw[i2] = conv_W[(size_t)(l * DD + w * 8 + o) * (13 * DD) + j];
    }
}

// ---------------- main per-layer kernel ----------------
// 768 threads = 12 waves = 3 chunk-groups x 4 output-slice waves. 1 block/CU.
// Weights for all 4 slices staged in LDS ONCE per block (53 KB) -> Phase B weight
// reads are broadcast ds_reads instead of per-chunk scalar-load streams (the r2
// bottleneck: ~100K cyc/chunk of s_load stall).
// Phase A: wave-per-node (4 nodes/wave), lane = d + 32*parity; shfl_xor(32) combine.
// Phase B: lane = task, wave computes 8 output dims; feats via XOR-swizzled LDS.
__launch_bounds__(768, 3)
__global__ void k_layer(const float* __restrict__ xin, float* __restrict__ xout,
                        const int* __restrict__ row_ptr, const int* __restrict__ es,
                        const float* __restrict__ rel_l, const float* __restrict__ pw_l,
                        const float* __restrict__ rdeg, const float* __restrict__ scale,
                        const float* __restrict__ invs,
                        const int* __restrict__ h_index, const int* __restrict__ r_index,
                        const float* __restrict__ query_emb, const float* __restrict__ conv_b_l,
                        int* __restrict__ ctr) {
    __shared__ __align__(16) float s_pw[4 * 3328];       // 53248 B: weights, all 4 slices
    __shared__ __align__(16) float s_agg[3][64 * 128];   // 98304 B: feats, 3 chunk-groups
    __shared__ float s_sc[3][64], s_iv[3][64];
    __shared__ float s_q[BB][DD];
    __shared__ int s_h[BB];
    __shared__ int s_base;
    const int tid = threadIdx.x;

    // one-time staging: weights -> LDS (float4, coalesced; L2-resident across blocks)
    {
        const float4* p4 = (const float4*)pw_l;
        float4* s4 = (float4*)s_pw;
        for (int i = tid; i < 3328; i += 768) s4[i] = p4[i];
    }
    if (tid < BB * DD) {
        int b = tid >> 5, dd = tid & 31;
        s_q[b][dd] = query_emb[r_index[b] * DD + dd];
    }
    if (tid < BB) s_h[tid] = h_index[tid];

    const int wv = tid >> 6;                      // 0..11
    const int cidx = wv >> 2;                     // chunk-group 0..2
    const int wq = __builtin_amdgcn_readfirstlane(wv & 3);  // output slice
    const int lane = tid & 63;
    const int d = lane & 31;
    const int par = lane >> 5;
    const float* pwb = s_pw + wq * 3328;          // LDS, wave-uniform -> broadcast reads
    float bias[8];
    #pragma unroll
    for (int oo = 0; oo < 8; ++oo) bias[oo] = conv_b_l[wq * 8 + oo];

    while (true) {
        __syncthreads();   // prev iteration's readers done; also covers staging 1st time
        if (tid == 0) s_base = atomicAdd(ctr, 3);
        __syncthreads();
        const int base = s_base;
        if (base >= NCHUNKS) break;               // uniform
        const int chunk = base + cidx;
        const bool active = chunk < NCHUNKS;      // group-uniform; barriers stay outside

        // ---------- Phase A ----------
        if (active) {
            #pragma unroll 1
            for (int i4 = 0; i4 < 4; ++i4) {
                const int nl = wq * 4 + i4;
                const int n = chunk * 16 + nl;
                float sa[4], sq[4], mx[4], mn[4];
                #pragma unroll
                for (int b = 0; b < 4; ++b) {
                    float bv = (n == s_h[b]) ? s_q[b][d] : 0.f;
                    float bs = par ? 0.f : bv;      // count boundary once in sum/sq
                    sa[b] = bs; sq[b] = bs * bv; mx[b] = bv; mn[b] = bv;
                }
                auto proc = [&](int ee) {
                    int pk = es[ee];
                    const float* xr = xin + (size_t)(pk & 0xFFFF) * 128 + d;
                    const float* rr = rel_l + (pk >> 16) * (BB * DD) + d;
                    #pragma unroll
                    for (int b = 0; b < 4; ++b) {
                        float m = xr[b * 32] * rr[b * 32];
                        sa[b] += m; sq[b] = fmaf(m, m, sq[b]);
                        mx[b] = fmaxf(mx[b], m); mn[b] = fminf(mn[b], m);
                    }
                };
                int e0 = row_ptr[n], e1 = row_ptr[n + 1];
                int e = e0 + par;                    // parity-strided
                for (; e + 2 < e1; e += 4) { proc(e); proc(e + 2); }
                for (; e < e1; e += 2) proc(e);
                #pragma unroll
                for (int b = 0; b < 4; ++b) {
                    sa[b] += __shfl_xor(sa[b], 32);
                    sq[b] += __shfl_xor(sq[b], 32);
                    mx[b] = fmaxf(mx[b], __shfl_xor(mx[b], 32));
                    mn[b] = fminf(mn[b], __shfl_xor(mn[b], 32));
                }
                float rd_ = rdeg[n];
                float mean[4], sd[4];
                #pragma unroll
                for (int b = 0; b < 4; ++b) {
                    mean[b] = sa[b] * rd_;
                    float sm = sq[b] * rd_;
                    sd[b] = sqrtf(fmaxf(sm - mean[b] * mean[b], 1e-6f));
                }
                int tA = nl * 4 + par * 2;
                int tB2 = tA + 1;
                float4 fA, fB;
                fA.x = par ? mean[2] : mean[0]; fA.y = par ? mx[2] : mx[0];
                fA.z = par ? mn[2] : mn[0];     fA.w = par ? sd[2] : sd[0];
                fB.x = par ? mean[3] : mean[1]; fB.y = par ? mx[3] : mx[1];
                fB.z = par ? mn[3] : mn[1];     fB.w = par ? sd[3] : sd[1];
                *(float4*)&s_agg[cidx][tA * 128 + ((4 * d) ^ ((tA & 7) << 2))] = fA;
                *(float4*)&s_agg[cidx][tB2 * 128 + ((4 * d) ^ ((tB2 & 7) << 2))] = fB;
                if (lane < 4) { s_sc[cidx][nl * 4 + lane] = scale[n]; s_iv[cidx][nl * 4 + lane] = invs[n]; }
            }
        }
        __syncthreads();
        // ---------- Phase B: conv (weights from LDS: broadcast reads) ----------
        if (active) {
            const int t = lane;
            const int nl2 = t >> 2, b2 = t & 3;
            const int n2 = chunk * 16 + nl2;
            float y0[8], y1[8], y2[8];
            #pragma unroll
            for (int oo = 0; oo < 8; ++oo) { y0[oo] = bias[oo]; y1[oo] = 0.f; y2[oo] = 0.f; }
            // x part from global (coalesced, L2-hot: just written/gathered)
            const float* xg = xin + (size_t)(n2 * 4 + b2) * DD;
            #pragma unroll
            for (int j0 = 0; j0 < 32; j0 += 4) {
                float4 c = *(const float4*)(xg + j0);
                #pragma unroll
                for (int jj = 0; jj < 4; ++jj) {
                    const float* pp = pwb + (j0 + jj) * 8;
                    float cv = (&c.x)[jj];
                    #pragma unroll
                    for (int oo = 0; oo < 8; ++oo) y0[oo] = fmaf(cv, pp[oo], y0[oo]);
                }
            }
            // feats from swizzled LDS
            const float* pf = pwb + 256;
            const float* arow = s_agg[cidx] + t * 128;
            const int sw = (t & 7) << 2;
            #pragma unroll 2
            for (int j40 = 0; j40 < 128; j40 += 4) {
                float4 c = *(const float4*)(arow + (j40 ^ sw));
                #pragma unroll
                for (int jj = 0; jj < 4; ++jj) {
                    const float* pp = pf + (j40 + jj) * 24;
                    float cv = (&c.x)[jj];
                    #pragma unroll
                    for (int oo = 0; oo < 8; ++oo) {
                        y0[oo] = fmaf(cv, pp[oo], y0[oo]);
                        y1[oo] = fmaf(cv, pp[8 + oo], y1[oo]);
                        y2[oo] = fmaf(cv, pp[16 + oo], y2[oo]);
                    }
                }
            }
            float scn = s_sc[cidx][t], ivn = s_iv[cidx][t];
            float* xo = xout + (size_t)(n2 * 4 + b2) * DD + wq * 8;
            float4 o0, o1;
            o0.x = fmaxf(0.f, y0[0] + scn * y1[0] + ivn * y2[0]);
            o0.y = fmaxf(0.f, y0[1] + scn * y1[1] + ivn * y2[1]);
            o0.z = fmaxf(0.f, y0[2] + scn * y1[2] + ivn * y2[2]);
            o0.w = fmaxf(0.f, y0[3] + scn * y1[3] + ivn * y2[3]);
            o1.x = fmaxf(0.f, y0[4] + scn * y1[4] + ivn * y2[4]);
            o1.y = fmaxf(0.f, y0[5] + scn * y1[5] + ivn * y2[5]);
            o1.z = fmaxf(0.f, y0[6] + scn * y1[6] + ivn * y2[6]);
            o1.w = fmaxf(0.f, y0[7] + scn * y1[7] + ivn * y2[7]);
            *(float4*)&xo[0] = o0;
            *(float4*)&xo[4] = o1;
        }
    }
}

// ---------------- final scoring ----------------
__global__ void k_score(const float* __restrict__ xL, const float* __restrict__ query_emb,
                        const int* __restrict__ r_index, const int* __restrict__ t_index,
                        const float* __restrict__ W1, const float* __restrict__ b1,
                        const float* __restrict__ W2, const float* __restrict__ b2,
                        float* __restrict__ out) {
    int bi = blockIdx.x;            // 0..127
    int b = bi >> 5, kk = bi & 31;
    int j = threadIdx.x;            // 0..63
    __shared__ float sf[64];
    int t = t_index[b * KK + kk];
    float f = (j < DD) ? xL[(size_t)(t * 4 + b) * DD + j]
                       : query_emb[r_index[b] * DD + (j - DD)];
    sf[j] = f;
    __syncthreads();
    float acc = b1[j];
    #pragma unroll 8
    for (int i2 = 0; i2 < 64; ++i2) acc = fmaf(sf[i2], W1[j * 64 + i2], acc);
    float h = fmaxf(acc, 0.f);
    float prod = h * W2[j];
    #pragma unroll
    for (int off = 32; off > 0; off >>= 1) prod += __shfl_down(prod, off);
    if (j == 0) out[b * KK + kk] = prod + b2[0];
}

extern "C" void kernel_launch(void* const* d_in, const int* in_sizes, int n_in,
                              void* d_out, int out_size, void* d_ws, size_t ws_size,
                              hipStream_t stream) {
    const int* ei        = (const int*)d_in[0];
    const int* et        = (const int*)d_in[1];
    const int* h_index   = (const int*)d_in[2];
    const int* t_index   = (const int*)d_in[3];
    const int* r_index   = (const int*)d_in[4];
    const float* query_emb = (const float*)d_in[6];
    const float* rel_W   = (const float*)d_in[7];
    const float* rel_b   = (const float*)d_in[8];
    const float* conv_W  = (const float*)d_in[9];
    const float* conv_b  = (const float*)d_in[10];
    const float* W1      = (const float*)d_in[11];
    const float* b1      = (const float*)d_in[12];
    const float* W2      = (const float*)d_in[13];
    const float* b2      = (const float*)d_in[14];

    float* ws = (float*)d_ws;
    float* x0      = ws + OFF_X0;
    float* x1      = ws + OFF_X1;
    int*   row_ptr = (int*)(ws + OFF_RP);
    int*   cursor  = (int*)(ws + OFF_CUR);
    int*   es      = (int*)(ws + OFF_ES);
    float* rdeg    = ws + OFF_DEG;
    float* sc      = ws + OFF_SC;
    float* invs    = ws + OFF_INV;
    int*   ctr     = (int*)(ws + OFF_CTR);
    float* rel_all = ws + OFF_REL;
    float* pw      = ws + OFF_PW;
    float* out     = (float*)d_out;

    // prep
    k_init<<<1024, 256, 0, stream>>>(h_index, r_index, query_emb, x0, cursor, ctr);
    k_hist<<<(N_EDGES + 255) / 256, 256, 0, stream>>>(ei, cursor);
    k_scan<<<1, 1024, 0, stream>>>(cursor, row_ptr, rdeg, sc, invs);
    k_scatter<<<(N_EDGES + 255) / 256, 256, 0, stream>>>(ei, et, cursor, es);
    const int NPREP = LL * BB * RR * DD + LL * 4 * 3328;
    k_prep_w<<<(NPREP + 255) / 256, 256, 0, stream>>>(query_emb, r_index, rel_W, rel_b,
                                                      conv_W, rel_all, pw);

    // 4 BF layers, ping-pong x0/x1
    for (int l = 0; l < LL; ++l) {
        const float* xi = (l & 1) ? x1 : x0;
        float* xo = (l & 1) ? x0 : x1;
        k_layer<<<256, 768, 0, stream>>>(xi, xo, row_ptr, es,
                                         rel_all + (size_t)l * RR * BB * DD,
                                         pw + (size_t)l * 4 * 3328,
                                         rdeg, sc, invs, h_index, r_index, query_emb,
                                         conv_b + l * DD, ctr + l);
    }

    k_score<<<BB * KK, 64, 0, stream>>>(x0, query_emb, r_index, t_index, W1, b1, W2, b2, out);
}

// Round 4
// 377.956 us; speedup vs baseline: 1.1525x; 1.1027x over previous
//
#include <hip/hip_runtime.h>
#include <hip/hip_bf16.h>

// NBFNet Bellman-Ford pass, MI355X. N=20000, E=200000, B=4, K=32, D=32, R=36, L=4.
#define N_NODES 20000
#define N_EDGES 200000
#define BB 4
#define KK 32
#define DD 32
#define RR 36
#define LL 4
#define NCHUNKS (N_NODES / 16)   // 1250 = 250 * 5

// ---------------- ws layout (element offsets, 4B units) ----------------
constexpr size_t OFF_X0   = 0;                                        // float[B*N*D], x[(n*4+b)*32+d]
constexpr size_t OFF_X1   = OFF_X0 + (size_t)BB * N_NODES * DD;
constexpr size_t OFF_RP   = OFF_X1 + (size_t)BB * N_NODES * DD;       // int[N+1]
constexpr size_t OFF_CUR  = OFF_RP + 20032;                           // int[N]
constexpr size_t OFF_ES   = OFF_CUR + N_NODES;                        // int[E] src | type<<16
constexpr size_t OFF_DEG  = OFF_ES + N_EDGES;                         // float[N] 1/deg
constexpr size_t OFF_SC   = OFF_DEG + N_NODES;                        // float[N] scale
constexpr size_t OFF_INV  = OFF_SC + N_NODES;                         // float[N] 1/max(scale,.01)
constexpr size_t OFF_REL  = OFF_INV + N_NODES;                        // float[L*R*B*D] [l][ty][b][d]
constexpr size_t OFF_PW   = OFF_REL + (size_t)LL * RR * BB * DD;      // float[L*4*3328]
constexpr size_t OFF_F    = OFF_PW + (size_t)LL * 4 * 3328;           // float[NCHUNKS*32*64*4] = 41 MB

// ---------------- prep kernels ----------------

__global__ void k_init(const int* __restrict__ h_index, const int* __restrict__ r_index,
                       const float* __restrict__ query_emb, float* __restrict__ x0,
                       int* __restrict__ cursor) {
    int i = blockIdx.x * blockDim.x + threadIdx.x;
    int stride = gridDim.x * blockDim.x;
    for (int t = i; t < N_NODES; t += stride) cursor[t] = 0;
    for (int t = i; t < BB * N_NODES * DD; t += stride) {
        int d = t & 31; int nb = t >> 5; int b = nb & 3; int n = nb >> 2;
        float v = 0.f;
        if (n == h_index[b]) v = query_emb[r_index[b] * DD + d];
        x0[t] = v;
    }
}

__global__ void k_hist(const int* __restrict__ ei, int* __restrict__ cursor) {
    int e = blockIdx.x * blockDim.x + threadIdx.x;
    if (e < N_EDGES) atomicAdd(&cursor[ei[N_EDGES + e]], 1);
}

// Single block: scan histogram -> row_ptr/cursor, plus rdeg/scale/inv (deterministic).
__global__ void k_scan(int* __restrict__ cursor, int* __restrict__ row_ptr,
                       float* __restrict__ rdeg, float* __restrict__ scale,
                       float* __restrict__ invs) {
    __shared__ int s_tot[1024];
    __shared__ float s_f[1024];
    const int PER = (N_NODES + 1023) / 1024;   // 20
    int tid = threadIdx.x;
    int start = tid * PER;
    int vals[20];
    float dls[20];
    int total = 0;
    #pragma unroll
    for (int j = 0; j < PER; ++j) {
        int idx = start + j;
        int v = (idx < N_NODES) ? cursor[idx] : 0;
        vals[j] = v; total += v;
    }
    s_tot[tid] = total;
    __syncthreads();
    for (int off = 1; off < 1024; off <<= 1) {
        int t = (tid >= off) ? s_tot[tid - off] : 0;
        __syncthreads();
        s_tot[tid] += t;
        __syncthreads();
    }
    int prefix = s_tot[tid] - total;   // exclusive
    float dsum = 0.f;
    int run = prefix;
    #pragma unroll
    for (int j = 0; j < PER; ++j) {
        int idx = start + j;
        if (idx < N_NODES) {
            row_ptr[idx] = run;
            cursor[idx] = run;
            run += vals[j];
            float lg = logf((float)(vals[j] + 1));
            dls[j] = lg;
            dsum += lg;
        }
    }
    if (tid == 1023) row_ptr[N_NODES] = run;
    s_f[tid] = dsum;
    __syncthreads();
    for (int off = 512; off > 0; off >>= 1) {
        if (tid < off) s_f[tid] += s_f[tid + off];
        __syncthreads();
    }
    float mean = s_f[0] / (float)N_NODES;
    #pragma unroll
    for (int j = 0; j < PER; ++j) {
        int idx = start + j;
        if (idx < N_NODES) {
            float dg = (float)(vals[j] + 1);
            float sc = dls[j] / mean;
            rdeg[idx] = 1.f / dg;
            scale[idx] = sc;
            invs[idx] = 1.f / fmaxf(sc, 0.01f);
        }
    }
}

__global__ void k_scatter(const int* __restrict__ ei, const int* __restrict__ et,
                          int* __restrict__ cursor, int* __restrict__ es) {
    int e = blockIdx.x * blockDim.x + threadIdx.x;
    if (e < N_EDGES) {
        int dnode = ei[N_EDGES + e];
        int p = atomicAdd(&cursor[dnode], 1);
        es[p] = ei[e] | (et[e] << 16);
    }
}

// rel tables [l][ty][b][d] + prepped conv weights (per (l,w): x[32][8] then feats[128][3][8]).
__global__ void k_prep_w(const float* __restrict__ query_emb, const int* __restrict__ r_index,
                         const float* __restrict__ rel_W, const float* __restrict__ rel_b,
                         const float* __restrict__ conv_W,
                         float* __restrict__ rel_all, float* __restrict__ pw) {
    int i = blockIdx.x * blockDim.x + threadIdx.x;
    const int NREL = LL * BB * RR * DD;
    if (i < NREL) {
        int d = i & 31;
        int ty = (i >> 5) % RR;
        int b = (i / (32 * RR)) & 3;
        int l = i / (32 * RR * BB);
        const float* q = query_emb + r_index[b] * DD;
        const float* w = rel_W + ((size_t)l * RR * DD + ty * DD + d) * DD;
        float acc = rel_b[l * RR * DD + ty * DD + d];
        #pragma unroll
        for (int k2 = 0; k2 < DD; ++k2) acc = fmaf(q[k2], w[k2], acc);
        rel_all[(((size_t)l * RR + ty) * BB + b) * DD + d] = acc;
    } else {
        int i2 = i - NREL;
        if (i2 >= LL * 4 * 3328) return;
        int r = i2 % 3328; int lw = i2 / 3328;
        int w = lw & 3, l = lw >> 2;
        int o, j;
        if (r < 256) { j = r >> 3; o = r & 7; }
        else {
            int r2 = r - 256;
            int j4 = r2 / 24; int ko = r2 % 24;
            int k2 = ko >> 3; o = ko & 7;
            j = DD + j4 * 3 + k2;
        }
        pw[i2] = conv_W[(size_t)(l * DD + w * 8 + o) * (13 * DD) + j];
    }
}

// ---------------- gather + PNA kernel ----------------
// Wave per node (grid-stride). Lane = (par, d): d = lane&31, par = lane>>5;
// parity halves process alternate edges, combined via shfl_xor(32).
// Writes F transposed: Fq[(chunk*32 + d)*64 + task] = {mean,max,min,std} (float4),
// so k_conv reads are fully coalesced (64 lanes x 16B contiguous).
__launch_bounds__(256, 4)
__global__ void k_gather(const float* __restrict__ xin, float4* __restrict__ Fq,
                         const int* __restrict__ row_ptr, const int* __restrict__ es,
                         const float* __restrict__ rel_l, const float* __restrict__ rdeg,
                         const int* __restrict__ h_index, const int* __restrict__ r_index,
                         const float* __restrict__ query_emb) {
    __shared__ __align__(16) float s_rel[RR * BB * DD];   // 18432 B
    const int tid = threadIdx.x;
    {   // stage rel table once per block
        const float4* p4 = (const float4*)rel_l;
        float4* s4 = (float4*)s_rel;
        for (int i = tid; i < RR * BB * DD / 4; i += 256) s4[i] = p4[i];
    }
    const int lane = tid & 63;
    const int d = lane & 31;
    const int par = lane >> 5;
    int hb[4]; float qv[4];
    #pragma unroll
    for (int b = 0; b < 4; ++b) {
        hb[b] = h_index[b];
        qv[b] = query_emb[r_index[b] * DD + d];
    }
    __syncthreads();

    const int nwaves = gridDim.x * 4;
    for (int n = blockIdx.x * 4 + (tid >> 6); n < N_NODES; n += nwaves) {
        float sa[4], sq[4], mx[4], mn[4];
        #pragma unroll
        for (int b = 0; b < 4; ++b) {
            float bv = (n == hb[b]) ? qv[b] : 0.f;
            float bs = par ? 0.f : bv;        // count boundary message once in sum/sq
            sa[b] = bs; sq[b] = bs * bv; mx[b] = bv; mn[b] = bv;
        }
        auto proc = [&](int ee) {
            int pk = es[ee];
            const float* xr = xin + (size_t)(pk & 0xFFFF) * 128 + d;
            const float* rr = s_rel + (pk >> 16) * 128 + d;
            #pragma unroll
            for (int b = 0; b < 4; ++b) {
                float m = xr[b * 32] * rr[b * 32];
                sa[b] += m; sq[b] = fmaf(m, m, sq[b]);
                mx[b] = fmaxf(mx[b], m); mn[b] = fminf(mn[b], m);
            }
        };
        int e0 = row_ptr[n], e1 = row_ptr[n + 1];
        int e = e0 + par;                        // parity-strided: 2 edges per step
        for (; e + 2 < e1; e += 4) { proc(e); proc(e + 2); }
        for (; e < e1; e += 2) proc(e);
        #pragma unroll
        for (int b = 0; b < 4; ++b) {
            sa[b] += __shfl_xor(sa[b], 32);
            sq[b] += __shfl_xor(sq[b], 32);
            mx[b] = fmaxf(mx[b], __shfl_xor(mx[b], 32));
            mn[b] = fminf(mn[b], __shfl_xor(mn[b], 32));
        }
        float rd_ = rdeg[n];
        float mean[4], sd[4];
        #pragma unroll
        for (int b = 0; b < 4; ++b) {
            mean[b] = sa[b] * rd_;
            float sm = sq[b] * rd_;
            sd[b] = sqrtf(fmaxf(sm - mean[b] * mean[b], 1e-6f));
        }
        const int chunk = n >> 4, nl = n & 15;
        int tA = nl * 4 + par * 2;               // each half writes 2 tasks
        float4 fA, fB;
        fA.x = par ? mean[2] : mean[0]; fA.y = par ? mx[2] : mx[0];
        fA.z = par ? mn[2] : mn[0];     fA.w = par ? sd[2] : sd[0];
        fB.x = par ? mean[3] : mean[1]; fB.y = par ? mx[3] : mx[1];
        fB.z = par ? mn[3] : mn[1];     fB.w = par ? sd[3] : sd[1];
        Fq[(size_t)(chunk * 32 + d) * 64 + tA] = fA;
        Fq[(size_t)(chunk * 32 + d) * 64 + tA + 1] = fB;
    }
}

// ---------------- conv kernel ----------------
// Grid 250 blocks x 256 thr (4 waves). Block owns 5 chunks (T=5 amortization:
// each broadcast weight read feeds 5 tasks/lane -> weight-read pipe below VALU floor).
// Wave wq computes outputs [wq*8, wq*8+8); lane = task within chunk.
// Weights staged once per block in LDS (53 KB), read as uniform (broadcast) float4.
__launch_bounds__(256, 2)
__global__ void k_conv(const float* __restrict__ xin, float* __restrict__ xout,
                       const float4* __restrict__ Fq, const float* __restrict__ pw_l,
                       const float* __restrict__ scale, const float* __restrict__ invs,
                       const float* __restrict__ conv_b_l) {
    __shared__ __align__(16) float4 s_pw[4 * 832];   // 53248 B
    const int tid = threadIdx.x;
    {
        const float4* p4 = (const float4*)pw_l;
        for (int i = tid; i < 4 * 832; i += 256) s_pw[i] = p4[i];
    }
    const int wq = __builtin_amdgcn_readfirstlane(tid >> 6);
    const int lane = tid & 63;
    const float4* wx = s_pw + wq * 832;       // x-part: 64 quads (per j: 2)
    const float4* wf = wx + 64;               // feats: per jj: 24 quads
    float bias[8];
    #pragma unroll
    for (int oo = 0; oo < 8; ++oo) bias[oo] = conv_b_l[wq * 8 + oo];
    __syncthreads();

    const int set = blockIdx.x;               // 0..249, chunks set*5 .. set*5+4
    const int nl2 = lane >> 2, b2 = lane & 3;

    float y[5][3][8];
    #pragma unroll
    for (int cc = 0; cc < 5; ++cc)
        #pragma unroll
        for (int oo = 0; oo < 8; ++oo) {
            y[cc][0][oo] = bias[oo]; y[cc][1][oo] = 0.f; y[cc][2][oo] = 0.f;
        }

    // ---- x part: K rows 0..31 ----
    #pragma unroll 2
    for (int jj = 0; jj < 8; ++jj) {
        float4 cx[5];
        #pragma unroll
        for (int cc = 0; cc < 5; ++cc) {
            int n = (set * 5 + cc) * 16 + nl2;
            cx[cc] = *(const float4*)(xin + (size_t)(n * 4 + b2) * DD + jj * 4);
        }
        #pragma unroll
        for (int dj = 0; dj < 4; ++dj) {
            float4 wA = wx[(jj * 4 + dj) * 2];
            float4 wB = wx[(jj * 4 + dj) * 2 + 1];
            #pragma unroll
            for (int cc = 0; cc < 5; ++cc) {
                float cv = (&cx[cc].x)[dj];
                y[cc][0][0] = fmaf(cv, wA.x, y[cc][0][0]);
                y[cc][0][1] = fmaf(cv, wA.y, y[cc][0][1]);
                y[cc][0][2] = fmaf(cv, wA.z, y[cc][0][2]);
                y[cc][0][3] = fmaf(cv, wA.w, y[cc][0][3]);
                y[cc][0][4] = fmaf(cv, wB.x, y[cc][0][4]);
                y[cc][0][5] = fmaf(cv, wB.y, y[cc][0][5]);
                y[cc][0][6] = fmaf(cv, wB.z, y[cc][0][6]);
                y[cc][0][7] = fmaf(cv, wB.w, y[cc][0][7]);
            }
        }
    }

    // ---- feats: 32 jj-blocks (= feat dim d), each with f = mean/max/min/std ----
    for (int jj = 0; jj < 32; ++jj) {
        float4 cf[5];
        #pragma unroll
        for (int cc = 0; cc < 5; ++cc)
            cf[cc] = Fq[(size_t)((set * 5 + cc) * 32 + jj) * 64 + lane];
        #pragma unroll
        for (int f = 0; f < 4; ++f) {
            const float4* wp = wf + jj * 24 + f * 6;
            float4 w0 = wp[0], w1 = wp[1], w2 = wp[2], w3 = wp[3], w4 = wp[4], w5 = wp[5];
            #pragma unroll
            for (int cc = 0; cc < 5; ++cc) {
                float cv = (&cf[cc].x)[f];
                y[cc][0][0] = fmaf(cv, w0.x, y[cc][0][0]);
                y[cc][0][1] = fmaf(cv, w0.y, y[cc][0][1]);
                y[cc][0][2] = fmaf(cv, w0.z, y[cc][0][2]);
                y[cc][0][3] = fmaf(cv, w0.w, y[cc][0][3]);
                y[cc][0][4] = fmaf(cv, w1.x, y[cc][0][4]);
                y[cc][0][5] = fmaf(cv, w1.y, y[cc][0][5]);
                y[cc][0][6] = fmaf(cv, w1.z, y[cc][0][6]);
                y[cc][0][7] = fmaf(cv, w1.w, y[cc][0][7]);
                y[cc][1][0] = fmaf(cv, w2.x, y[cc][1][0]);
                y[cc][1][1] = fmaf(cv, w2.y, y[cc][1][1]);
                y[cc][1][2] = fmaf(cv, w2.z, y[cc][1][2]);
                y[cc][1][3] = fmaf(cv, w2.w, y[cc][1][3]);
                y[cc][1][4] = fmaf(cv, w3.x, y[cc][1][4]);
                y[cc][1][5] = fmaf(cv, w3.y, y[cc][1][5]);
                y[cc][1][6] = fmaf(cv, w3.z, y[cc][1][6]);
                y[cc][1][7] = fmaf(cv, w3.w, y[cc][1][7]);
                y[cc][2][0] = fmaf(cv, w4.x, y[cc][2][0]);
                y[cc][2][1] = fmaf(cv, w4.y, y[cc][2][1]);
                y[cc][2][2] = fmaf(cv, w4.z, y[cc][2][2]);
                y[cc][2][3] = fmaf(cv, w4.w, y[cc][2][3]);
                y[cc][2][4] = fmaf(cv, w5.x, y[cc][2][4]);
                y[cc][2][5] = fmaf(cv, w5.y, y[cc][2][5]);
                y[cc][2][6] = fmaf(cv, w5.z, y[cc][2][6]);
                y[cc][2][7] = fmaf(cv, w5.w, y[cc][2][7]);
            }
        }
    }

    // ---- epilogue ----
    #pragma unroll
    for (int cc = 0; cc < 5; ++cc) {
        int n = (set * 5 + cc) * 16 + nl2;
        float scn = scale[n], ivn = invs[n];
        float* xo = xout + (size_t)(n * 4 + b2) * DD + wq * 8;
        float4 o0, o1;
        o0.x = fmaxf(0.f, y[cc][0][0] + scn * y[cc][1][0] + ivn * y[cc][2][0]);
        o0.y = fmaxf(0.f, y[cc][0][1] + scn * y[cc][1][1] + ivn * y[cc][2][1]);
        o0.z = fmaxf(0.f, y[cc][0][2] + scn * y[cc][1][2] + ivn * y[cc][2][2]);
        o0.w = fmaxf(0.f, y[cc][0][3] + scn * y[cc][1][3] + ivn * y[cc][2][3]);
        o1.x = fmaxf(0.f, y[cc][0][4] + scn * y[cc][1][4] + ivn * y[cc][2][4]);
        o1.y = fmaxf(0.f, y[cc][0][5] + scn * y[cc][1][5] + ivn * y[cc][2][5]);
        o1.z = fmaxf(0.f, y[cc][0][6] + scn * y[cc][1][6] + ivn * y[cc][2][6]);
        o1.w = fmaxf(0.f, y[cc][0][7] + scn * y[cc][1][7] + ivn * y[cc][2][7]);
        *(float4*)&xo[0] = o0;
        *(float4*)&xo[4] = o1;
    }
}

// ---------------- final scoring ----------------
__global__ void k_score(const float* __restrict__ xL, const float* __restrict__ query_emb,
                        const int* __restrict__ r_index, const int* __restrict__ t_index,
                        const float* __restrict__ W1, const float* __restrict__ b1,
                        const float* __restrict__ W2, const float* __restrict__ b2,
                        float* __restrict__ out) {
    int bi = blockIdx.x;            // 0..127
    int b = bi >> 5, kk = bi & 31;
    int j = threadIdx.x;            // 0..63
    __shared__ float sf[64];
    int t = t_index[b * KK + kk];
    float f = (j < DD) ? xL[(size_t)(t * 4 + b) * DD + j]
                       : query_emb[r_index[b] * DD + (j - DD)];
    sf[j] = f;
    __syncthreads();
    float acc = b1[j];
    #pragma unroll 8
    for (int i2 = 0; i2 < 64; ++i2) acc = fmaf(sf[i2], W1[j * 64 + i2], acc);
    float h = fmaxf(acc, 0.f);
    float prod = h * W2[j];
    #pragma unroll
    for (int off = 32; off > 0; off >>= 1) prod += __shfl_down(prod, off);
    if (j == 0) out[b * KK + kk] = prod + b2[0];
}

extern "C" void kernel_launch(void* const* d_in, const int* in_sizes, int n_in,
                              void* d_out, int out_size, void* d_ws, size_t ws_size,
                              hipStream_t stream) {
    const int* ei        = (const int*)d_in[0];
    const int* et        = (const int*)d_in[1];
    const int* h_index   = (const int*)d_in[2];
    const int* t_index   = (const int*)d_in[3];
    const int* r_index   = (const int*)d_in[4];
    const float* query_emb = (const float*)d_in[6];
    const float* rel_W   = (const float*)d_in[7];
    const float* rel_b   = (const float*)d_in[8];
    const float* conv_W  = (const float*)d_in[9];
    const float* conv_b  = (const float*)d_in[10];
    const float* W1      = (const float*)d_in[11];
    const float* b1      = (const float*)d_in[12];
    const float* W2      = (const float*)d_in[13];
    const float* b2      = (const float*)d_in[14];

    float* ws = (float*)d_ws;
    float* x0      = ws + OFF_X0;
    float* x1      = ws + OFF_X1;
    int*   row_ptr = (int*)(ws + OFF_RP);
    int*   cursor  = (int*)(ws + OFF_CUR);
    int*   es      = (int*)(ws + OFF_ES);
    float* rdeg    = ws + OFF_DEG;
    float* sc      = ws + OFF_SC;
    float* invs    = ws + OFF_INV;
    float* rel_all = ws + OFF_REL;
    float* pw      = ws + OFF_PW;
    float4* Fq     = (float4*)(ws + OFF_F);
    float* out     = (float*)d_out;

    // prep
    k_init<<<1024, 256, 0, stream>>>(h_index, r_index, query_emb, x0, cursor);
    k_hist<<<(N_EDGES + 255) / 256, 256, 0, stream>>>(ei, cursor);
    k_scan<<<1, 1024, 0, stream>>>(cursor, row_ptr, rdeg, sc, invs);
    k_scatter<<<(N_EDGES + 255) / 256, 256, 0, stream>>>(ei, et, cursor, es);
    const int NPREP = LL * BB * RR * DD + LL * 4 * 3328;
    k_prep_w<<<(NPREP + 255) / 256, 256, 0, stream>>>(query_emb, r_index, rel_W, rel_b,
                                                      conv_W, rel_all, pw);

    // 4 BF layers, ping-pong x0/x1
    for (int l = 0; l < LL; ++l) {
        const float* xi = (l & 1) ? x1 : x0;
        float* xo = (l & 1) ? x0 : x1;
        k_gather<<<1280, 256, 0, stream>>>(xi, Fq, row_ptr, es,
                                           rel_all + (size_t)l * RR * BB * DD,
                                           rdeg, h_index, r_index, query_emb);
        k_conv<<<250, 256, 0, stream>>>(xi, xo, Fq, pw + (size_t)l * 4 * 3328,
                                        sc, invs, conv_b + l * DD);
    }

    k_score<<<BB * KK, 64, 0, stream>>>(x0, query_emb, r_index, t_index, W1, b1, W2, b2, out);
}

// Round 5
// 368.366 us; speedup vs baseline: 1.1825x; 1.0260x over previous
//
#include <hip/hip_runtime.h>
#include <hip/hip_bf16.h>

// NBFNet Bellman-Ford pass, MI355X. N=20000, E=200000, B=4, K=32, D=32, R=36, L=4.
// x layout: [n][d][b] (b innermost) -> gather reads one dwordx4 per edge per lane.
#define N_NODES 20000
#define N_EDGES 200000
#define BB 4
#define KK 32
#define DD 32
#define RR 36
#define LL 4
#define NCHUNKS (N_NODES / 16)   // 1250 = 250 * 5
#define NBLK 79                  // ceil(20000/256)

// ---------------- ws layout (element offsets, 4B units) ----------------
constexpr size_t OFF_X0   = 0;                                        // float[N*D*B], x[(n*32+d)*4+b]
constexpr size_t OFF_X1   = OFF_X0 + (size_t)BB * N_NODES * DD;
constexpr size_t OFF_RP   = OFF_X1 + (size_t)BB * N_NODES * DD;       // int[N+1]
constexpr size_t OFF_CUR  = OFF_RP + 20032;                           // int[N]
constexpr size_t OFF_ES   = OFF_CUR + N_NODES;                        // int[E] src | type<<16
constexpr size_t OFF_DEG  = OFF_ES + N_EDGES;                         // float[N] 1/deg
constexpr size_t OFF_SC   = OFF_DEG + N_NODES;                        // float[N] scale
constexpr size_t OFF_INV  = OFF_SC + N_NODES;                         // float[N] 1/max(scale,.01)
constexpr size_t OFF_BS   = OFF_INV + N_NODES;                        // int[128] block sums
constexpr size_t OFF_BL   = OFF_BS + 128;                             // float[128] block log sums
constexpr size_t OFF_BO   = OFF_BL + 128;                             // int[128] block offsets
constexpr size_t OFF_MEAN = OFF_BO + 128;                             // float[16]
constexpr size_t OFF_REL  = OFF_MEAN + 16;                            // float[L*R*D*B] [l][ty][d][b]
constexpr size_t OFF_PW   = OFF_REL + (size_t)LL * RR * BB * DD;      // float[L*4*3328]
constexpr size_t OFF_F    = OFF_PW + (size_t)LL * 4 * 3328;           // float4[NCHUNKS*32*64] = 41 MB

// ---------------- prep kernels ----------------

__global__ void k_init(const int* __restrict__ h_index, const int* __restrict__ r_index,
                       const float* __restrict__ query_emb, float* __restrict__ x0,
                       int* __restrict__ cursor) {
    int i = blockIdx.x * blockDim.x + threadIdx.x;
    int stride = gridDim.x * blockDim.x;
    for (int t = i; t < N_NODES; t += stride) cursor[t] = 0;
    for (int t = i; t < BB * N_NODES * DD; t += stride) {
        int b = t & 3; int d = (t >> 2) & 31; int n = t >> 7;
        float v = 0.f;
        if (n == h_index[b]) v = query_emb[r_index[b] * DD + d];
        x0[t] = v;
    }
}

__global__ void k_hist(const int* __restrict__ ei, int* __restrict__ cursor) {
    int e = blockIdx.x * blockDim.x + threadIdx.x;
    if (e < N_EDGES) atomicAdd(&cursor[ei[N_EDGES + e]], 1);
}

// per-block partial sums of deg histogram + log(deg)
__global__ void k_part(const int* __restrict__ cursor, int* __restrict__ bsum,
                       float* __restrict__ blog) {
    __shared__ int si[256];
    __shared__ float sf2[256];
    int tid = threadIdx.x;
    int i = blockIdx.x * 256 + tid;
    int v = (i < N_NODES) ? cursor[i] : 0;
    float lg = (i < N_NODES) ? logf((float)(v + 1)) : 0.f;
    si[tid] = v; sf2[tid] = lg;
    __syncthreads();
    for (int off = 128; off > 0; off >>= 1) {
        if (tid < off) { si[tid] += si[tid + off]; sf2[tid] += sf2[tid + off]; }
        __syncthreads();
    }
    if (tid == 0) { bsum[blockIdx.x] = si[0]; blog[blockIdx.x] = sf2[0]; }
}

// single small block: scan the 79 block sums; total log -> mean
__global__ void k_scan2(const int* __restrict__ bsum, const float* __restrict__ blog,
                        int* __restrict__ boff, float* __restrict__ meanw) {
    __shared__ int si[128];
    __shared__ float sf2[128];
    int t = threadIdx.x;
    int v = (t < NBLK) ? bsum[t] : 0;
    float lg = (t < NBLK) ? blog[t] : 0.f;
    si[t] = v; sf2[t] = lg;
    __syncthreads();
    for (int off = 1; off < 128; off <<= 1) {
        int tv = (t >= off) ? si[t - off] : 0;
        float tf = (t >= off) ? sf2[t - off] : 0.f;
        __syncthreads();
        si[t] += tv; sf2[t] += tf;
        __syncthreads();
    }
    if (t < NBLK) boff[t] = si[t] - v;                      // exclusive
    if (t == 127) meanw[0] = sf2[127] / (float)N_NODES;     // mean(log deg)
}

// per-block scan + global offset -> row_ptr/cursor; rdeg/scale/inv
__global__ void k_final(int* __restrict__ cursor, int* __restrict__ row_ptr,
                        const int* __restrict__ boff, const float* __restrict__ meanw,
                        float* __restrict__ rdeg, float* __restrict__ scale,
                        float* __restrict__ invs) {
    __shared__ int si[256];
    int tid = threadIdx.x;
    int i = blockIdx.x * 256 + tid;
    int v = (i < N_NODES) ? cursor[i] : 0;
    si[tid] = v;
    __syncthreads();
    for (int off = 1; off < 256; off <<= 1) {
        int tv = (tid >= off) ? si[tid - off] : 0;
        __syncthreads();
        si[tid] += tv;
        __syncthreads();
    }
    int rp = boff[blockIdx.x] + si[tid] - v;   // exclusive prefix
    if (i < N_NODES) {
        row_ptr[i] = rp;
        cursor[i] = rp;
        float dg = (float)(v + 1);
        float sc = logf(dg) / meanw[0];
        rdeg[i] = 1.f / dg;
        scale[i] = sc;
        invs[i] = 1.f / fmaxf(sc, 0.01f);
    }
    if (i == 0) row_ptr[N_NODES] = N_EDGES;
}

__global__ void k_scatter(const int* __restrict__ ei, const int* __restrict__ et,
                          int* __restrict__ cursor, int* __restrict__ es) {
    int e = blockIdx.x * blockDim.x + threadIdx.x;
    if (e < N_EDGES) {
        int dnode = ei[N_EDGES + e];
        int p = atomicAdd(&cursor[dnode], 1);
        es[p] = ei[e] | (et[e] << 16);
    }
}

// rel tables [l][ty][d][b] (float4 per (ty,d)) + prepped conv weights.
__global__ void k_prep_w(const float* __restrict__ query_emb, const int* __restrict__ r_index,
                         const float* __restrict__ rel_W, const float* __restrict__ rel_b,
                         const float* __restrict__ conv_W,
                         float* __restrict__ rel_all, float* __restrict__ pw) {
    int i = blockIdx.x * blockDim.x + threadIdx.x;
    const int NREL = LL * BB * RR * DD;
    if (i < NREL) {
        int d = i & 31;
        int ty = (i >> 5) % RR;
        int b = (i / (32 * RR)) & 3;
        int l = i / (32 * RR * BB);
        const float* q = query_emb + r_index[b] * DD;
        const float* w = rel_W + ((size_t)l * RR * DD + ty * DD + d) * DD;
        float acc = rel_b[l * RR * DD + ty * DD + d];
        #pragma unroll
        for (int k2 = 0; k2 < DD; ++k2) acc = fmaf(q[k2], w[k2], acc);
        rel_all[(((size_t)l * RR + ty) * DD + d) * BB + b] = acc;
    } else {
        int i2 = i - NREL;
        if (i2 >= LL * 4 * 3328) return;
        int r = i2 % 3328; int lw = i2 / 3328;
        int w = lw & 3, l = lw >> 2;
        int o, j;
        if (r < 256) { j = r >> 3; o = r & 7; }
        else {
            int r2 = r - 256;
            int j4 = r2 / 24; int ko = r2 % 24;
            int k2 = ko >> 3; o = ko & 7;
            j = DD + j4 * 3 + k2;
        }
        pw[i2] = conv_W[(size_t)(l * DD + w * 8 + o) * (13 * DD) + j];
    }
}

// ---------------- gather + PNA kernel ----------------
// Wave per node (grid-stride). lane = d + 32*par; parity halves process alternate
// edges (4-deep unroll = 8 x-row dwordx4 loads in flight per wave); shfl_xor(32) combine.
// x[n] row for all 4 b at lane d is ONE dwordx4 ([n][d][b] layout); rel likewise.
// Writes F transposed: Fq[(chunk*32 + d)*64 + task] = {mean,max,min,std}.
__launch_bounds__(256, 6)
__global__ void k_gather(const float* __restrict__ xin, float4* __restrict__ Fq,
                         const int* __restrict__ row_ptr, const int* __restrict__ es,
                         const float* __restrict__ rel_l, const float* __restrict__ rdeg,
                         const int* __restrict__ h_index, const int* __restrict__ r_index,
                         const float* __restrict__ query_emb) {
    __shared__ __align__(16) float s_rel[RR * BB * DD];   // 18432 B, [ty][d][b]
    const int tid = threadIdx.x;
    {   // stage rel table once per block
        const float4* p4 = (const float4*)rel_l;
        float4* s4 = (float4*)s_rel;
        for (int i = tid; i < RR * BB * DD / 4; i += 256) s4[i] = p4[i];
    }
    const int lane = tid & 63;
    const int d = lane & 31;
    const int par = lane >> 5;
    int hb[4]; float qv[4];
    #pragma unroll
    for (int b = 0; b < 4; ++b) {
        hb[b] = h_index[b];
        qv[b] = query_emb[r_index[b] * DD + d];
    }
    __syncthreads();

    const int nwaves = gridDim.x * 4;
    for (int n = blockIdx.x * 4 + (tid >> 6); n < N_NODES; n += nwaves) {
        float sa[4], sq[4], mx[4], mn[4];
        #pragma unroll
        for (int b = 0; b < 4; ++b) {
            float bv = (n == hb[b]) ? qv[b] : 0.f;
            float bs = par ? 0.f : bv;        // count boundary message once in sum/sq
            sa[b] = bs; sq[b] = bs * bv; mx[b] = bv; mn[b] = bv;
        }
        auto proc = [&](int ee) {
            int pk = es[ee];
            float4 xv = *(const float4*)(xin + ((size_t)(pk & 0xFFFF) * DD + d) * 4);
            float4 rv = *(const float4*)(s_rel + (((pk >> 16) * DD) + d) * 4);
            #pragma unroll
            for (int b = 0; b < 4; ++b) {
                float m = (&xv.x)[b] * (&rv.x)[b];
                sa[b] += m; sq[b] = fmaf(m, m, sq[b]);
                mx[b] = fmaxf(mx[b], m); mn[b] = fminf(mn[b], m);
            }
        };
        int e0 = row_ptr[n], e1 = row_ptr[n + 1];
        int e = e0 + par;                        // parity-strided: 2 edges per step
        for (; e + 6 < e1; e += 8) { proc(e); proc(e + 2); proc(e + 4); proc(e + 6); }
        for (; e < e1; e += 2) proc(e);
        #pragma unroll
        for (int b = 0; b < 4; ++b) {
            sa[b] += __shfl_xor(sa[b], 32);
            sq[b] += __shfl_xor(sq[b], 32);
            mx[b] = fmaxf(mx[b], __shfl_xor(mx[b], 32));
            mn[b] = fminf(mn[b], __shfl_xor(mn[b], 32));
        }
        float rd_ = rdeg[n];
        float mean[4], sd[4];
        #pragma unroll
        for (int b = 0; b < 4; ++b) {
            mean[b] = sa[b] * rd_;
            float sm = sq[b] * rd_;
            sd[b] = sqrtf(fmaxf(sm - mean[b] * mean[b], 1e-6f));
        }
        const int chunk = n >> 4, nl = n & 15;
        int tA = nl * 4 + par * 2;               // each half writes 2 tasks
        float4 fA, fB;
        fA.x = par ? mean[2] : mean[0]; fA.y = par ? mx[2] : mx[0];
        fA.z = par ? mn[2] : mn[0];     fA.w = par ? sd[2] : sd[0];
        fB.x = par ? mean[3] : mean[1]; fB.y = par ? mx[3] : mx[1];
        fB.z = par ? mn[3] : mn[1];     fB.w = par ? sd[3] : sd[1];
        Fq[(size_t)(chunk * 32 + d) * 64 + tA] = fA;
        Fq[(size_t)(chunk * 32 + d) * 64 + tA + 1] = fB;
    }
}

// ---------------- conv kernel ----------------
// Grid 250 x 256 (4 waves). Block owns 5 chunks (T=5: each broadcast weight read
// feeds 5 tasks/lane). Wave wq -> outputs [wq*8, wq*8+8); lane = task within chunk.
// Weights in LDS (53 KB, staged once), uniform float4 reads.
__launch_bounds__(256, 2)
__global__ void k_conv(const float* __restrict__ xin, float* __restrict__ xout,
                       const float4* __restrict__ Fq, const float* __restrict__ pw_l,
                       const float* __restrict__ scale, const float* __restrict__ invs,
                       const float* __restrict__ conv_b_l) {
    __shared__ __align__(16) float4 s_pw[4 * 832];   // 53248 B
    const int tid = threadIdx.x;
    {
        const float4* p4 = (const float4*)pw_l;
        for (int i = tid; i < 4 * 832; i += 256) s_pw[i] = p4[i];
    }
    const int wq = __builtin_amdgcn_readfirstlane(tid >> 6);
    const int lane = tid & 63;
    const float4* wx = s_pw + wq * 832;       // x-part: 64 quads
    const float4* wf = wx + 64;               // feats: per jj: 24 quads
    float bias[8];
    #pragma unroll
    for (int oo = 0; oo < 8; ++oo) bias[oo] = conv_b_l[wq * 8 + oo];
    __syncthreads();

    const int set = blockIdx.x;               // chunks set*5 .. set*5+4
    const int nl2 = lane >> 2, b2 = lane & 3;

    float y[5][3][8];
    #pragma unroll
    for (int cc = 0; cc < 5; ++cc)
        #pragma unroll
        for (int oo = 0; oo < 8; ++oo) {
            y[cc][0][oo] = bias[oo]; y[cc][1][oo] = 0.f; y[cc][2][oo] = 0.f;
        }

    // ---- x part: K rows 0..31 ([n][d][b] layout -> strided dword loads, L2-hot) ----
    #pragma unroll 2
    for (int jj = 0; jj < 8; ++jj) {
        float cxv[5][4];
        #pragma unroll
        for (int cc = 0; cc < 5; ++cc) {
            int n = (set * 5 + cc) * 16 + nl2;
            const float* xb = xin + (size_t)n * 128 + b2;
            #pragma unroll
            for (int dj = 0; dj < 4; ++dj)
                cxv[cc][dj] = xb[(jj * 4 + dj) * 4];
        }
        #pragma unroll
        for (int dj = 0; dj < 4; ++dj) {
            float4 wA = wx[(jj * 4 + dj) * 2];
            float4 wB = wx[(jj * 4 + dj) * 2 + 1];
            #pragma unroll
            for (int cc = 0; cc < 5; ++cc) {
                float cv = cxv[cc][dj];
                y[cc][0][0] = fmaf(cv, wA.x, y[cc][0][0]);
                y[cc][0][1] = fmaf(cv, wA.y, y[cc][0][1]);
                y[cc][0][2] = fmaf(cv, wA.z, y[cc][0][2]);
                y[cc][0][3] = fmaf(cv, wA.w, y[cc][0][3]);
                y[cc][0][4] = fmaf(cv, wB.x, y[cc][0][4]);
                y[cc][0][5] = fmaf(cv, wB.y, y[cc][0][5]);
                y[cc][0][6] = fmaf(cv, wB.z, y[cc][0][6]);
                y[cc][0][7] = fmaf(cv, wB.w, y[cc][0][7]);
            }
        }
    }

    // ---- feats: 32 d-blocks, f = mean/max/min/std ----
    for (int jj = 0; jj < 32; ++jj) {
        float4 cf[5];
        #pragma unroll
        for (int cc = 0; cc < 5; ++cc)
            cf[cc] = Fq[(size_t)((set * 5 + cc) * 32 + jj) * 64 + lane];
        #pragma unroll
        for (int f = 0; f < 4; ++f) {
            const float4* wp = wf + jj * 24 + f * 6;
            float4 w0 = wp[0], w1 = wp[1], w2 = wp[2], w3 = wp[3], w4 = wp[4], w5 = wp[5];
            #pragma unroll
            for (int cc = 0; cc < 5; ++cc) {
                float cv = (&cf[cc].x)[f];
                y[cc][0][0] = fmaf(cv, w0.x, y[cc][0][0]);
                y[cc][0][1] = fmaf(cv, w0.y, y[cc][0][1]);
                y[cc][0][2] = fmaf(cv, w0.z, y[cc][0][2]);
                y[cc][0][3] = fmaf(cv, w0.w, y[cc][0][3]);
                y[cc][0][4] = fmaf(cv, w1.x, y[cc][0][4]);
                y[cc][0][5] = fmaf(cv, w1.y, y[cc][0][5]);
                y[cc][0][6] = fmaf(cv, w1.z, y[cc][0][6]);
                y[cc][0][7] = fmaf(cv, w1.w, y[cc][0][7]);
                y[cc][1][0] = fmaf(cv, w2.x, y[cc][1][0]);
                y[cc][1][1] = fmaf(cv, w2.y, y[cc][1][1]);
                y[cc][1][2] = fmaf(cv, w2.z, y[cc][1][2]);
                y[cc][1][3] = fmaf(cv, w2.w, y[cc][1][3]);
                y[cc][1][4] = fmaf(cv, w3.x, y[cc][1][4]);
                y[cc][1][5] = fmaf(cv, w3.y, y[cc][1][5]);
                y[cc][1][6] = fmaf(cv, w3.z, y[cc][1][6]);
                y[cc][1][7] = fmaf(cv, w3.w, y[cc][1][7]);
                y[cc][2][0] = fmaf(cv, w4.x, y[cc][2][0]);
                y[cc][2][1] = fmaf(cv, w4.y, y[cc][2][1]);
                y[cc][2][2] = fmaf(cv, w4.z, y[cc][2][2]);
                y[cc][2][3] = fmaf(cv, w4.w, y[cc][2][3]);
                y[cc][2][4] = fmaf(cv, w5.x, y[cc][2][4]);
                y[cc][2][5] = fmaf(cv, w5.y, y[cc][2][5]);
                y[cc][2][6] = fmaf(cv, w5.z, y[cc][2][6]);
                y[cc][2][7] = fmaf(cv, w5.w, y[cc][2][7]);
            }
        }
    }

    // ---- epilogue: out[n][o][b] scalar stores (coalesced per o across lanes) ----
    #pragma unroll
    for (int cc = 0; cc < 5; ++cc) {
        int n = (set * 5 + cc) * 16 + nl2;
        float scn = scale[n], ivn = invs[n];
        float* xo = xout + (size_t)n * 128 + b2;
        #pragma unroll
        for (int oo = 0; oo < 8; ++oo) {
            float v = fmaxf(0.f, y[cc][0][oo] + scn * y[cc][1][oo] + ivn * y[cc][2][oo]);
            xo[(wq * 8 + oo) * 4] = v;
        }
    }
}

// ---------------- final scoring ----------------
__global__ void k_score(const float* __restrict__ xL, const float* __restrict__ query_emb,
                        const int* __restrict__ r_index, const int* __restrict__ t_index,
                        const float* __restrict__ W1, const float* __restrict__ b1,
                        const float* __restrict__ W2, const float* __restrict__ b2,
                        float* __restrict__ out) {
    int bi = blockIdx.x;            // 0..127
    int b = bi >> 5, kk = bi & 31;
    int j = threadIdx.x;            // 0..63
    __shared__ float sf[64];
    int t = t_index[b * KK + kk];
    float f = (j < DD) ? xL[(size_t)t * 128 + j * 4 + b]
                       : query_emb[r_index[b] * DD + (j - DD)];
    sf[j] = f;
    __syncthreads();
    float acc = b1[j];
    #pragma unroll 8
    for (int i2 = 0; i2 < 64; ++i2) acc = fmaf(sf[i2], W1[j * 64 + i2], acc);
    float h = fmaxf(acc, 0.f);
    float prod = h * W2[j];
    #pragma unroll
    for (int off = 32; off > 0; off >>= 1) prod += __shfl_down(prod, off);
    if (j == 0) out[b * KK + kk] = prod + b2[0];
}

extern "C" void kernel_launch(void* const* d_in, const int* in_sizes, int n_in,
                              void* d_out, int out_size, void* d_ws, size_t ws_size,
                              hipStream_t stream) {
    const int* ei        = (const int*)d_in[0];
    const int* et        = (const int*)d_in[1];
    const int* h_index   = (const int*)d_in[2];
    const int* t_index   = (const int*)d_in[3];
    const int* r_index   = (const int*)d_in[4];
    const float* query_emb = (const float*)d_in[6];
    const float* rel_W   = (const float*)d_in[7];
    const float* rel_b   = (const float*)d_in[8];
    const float* conv_W  = (const float*)d_in[9];
    const float* conv_b  = (const float*)d_in[10];
    const float* W1      = (const float*)d_in[11];
    const float* b1      = (const float*)d_in[12];
    const float* W2      = (const float*)d_in[13];
    const float* b2      = (const float*)d_in[14];

    float* ws = (float*)d_ws;
    float* x0      = ws + OFF_X0;
    float* x1      = ws + OFF_X1;
    int*   row_ptr = (int*)(ws + OFF_RP);
    int*   cursor  = (int*)(ws + OFF_CUR);
    int*   es      = (int*)(ws + OFF_ES);
    float* rdeg    = ws + OFF_DEG;
    float* sc      = ws + OFF_SC;
    float* invs    = ws + OFF_INV;
    int*   bsum    = (int*)(ws + OFF_BS);
    float* blog    = ws + OFF_BL;
    int*   boff    = (int*)(ws + OFF_BO);
    float* meanw   = ws + OFF_MEAN;
    float* rel_all = ws + OFF_REL;
    float* pw      = ws + OFF_PW;
    float4* Fq     = (float4*)(ws + OFF_F);
    float* out     = (float*)d_out;

    // prep
    k_init<<<1024, 256, 0, stream>>>(h_index, r_index, query_emb, x0, cursor);
    k_hist<<<(N_EDGES + 255) / 256, 256, 0, stream>>>(ei, cursor);
    k_part<<<NBLK, 256, 0, stream>>>(cursor, bsum, blog);
    k_scan2<<<1, 128, 0, stream>>>(bsum, blog, boff, meanw);
    k_final<<<NBLK, 256, 0, stream>>>(cursor, row_ptr, boff, meanw, rdeg, sc, invs);
    k_scatter<<<(N_EDGES + 255) / 256, 256, 0, stream>>>(ei, et, cursor, es);
    const int NPREP = LL * BB * RR * DD + LL * 4 * 3328;
    k_prep_w<<<(NPREP + 255) / 256, 256, 0, stream>>>(query_emb, r_index, rel_W, rel_b,
                                                      conv_W, rel_all, pw);

    // 4 BF layers, ping-pong x0/x1
    for (int l = 0; l < LL; ++l) {
        const float* xi = (l & 1) ? x1 : x0;
        float* xo = (l & 1) ? x0 : x1;
        k_gather<<<1536, 256, 0, stream>>>(xi, Fq, row_ptr, es,
                                           rel_all + (size_t)l * RR * BB * DD,
                                           rdeg, h_index, r_index, query_emb);
        k_conv<<<250, 256, 0, stream>>>(xi, xo, Fq, pw + (size_t)l * 4 * 3328,
                                        sc, invs, conv_b + l * DD);
    }

    k_score<<<BB * KK, 64, 0, stream>>>(x0, query_emb, r_index, t_index, W1, b1, W2, b2, out);
}

// Round 6
// 343.956 us; speedup vs baseline: 1.2664x; 1.0710x over previous
//
#include <hip/hip_runtime.h>
#include <hip/hip_bf16.h>

// NBFNet Bellman-Ford pass, MI355X. N=20000, E=200000, B=4, K=32, D=32, R=36, L=4.
// x layout: [n][d][b] (b innermost) -> gather reads one dwordx4 per edge per lane.
#define N_NODES 20000
#define N_EDGES 200000
#define BB 4
#define KK 32
#define DD 32
#define RR 36
#define LL 4
#define NCHUNKS (N_NODES / 16)   // 1250 = 250 * 5
#define NBLK 79                  // ceil(20000/256)

// ---------------- ws layout (element offsets, 4B units) ----------------
constexpr size_t OFF_X0   = 0;                                        // float[N*D*B], x[(n*32+d)*4+b]
constexpr size_t OFF_X1   = OFF_X0 + (size_t)BB * N_NODES * DD;
constexpr size_t OFF_RP   = OFF_X1 + (size_t)BB * N_NODES * DD;       // int[N+1]
constexpr size_t OFF_CUR  = OFF_RP + 20032;                           // int[N]
constexpr size_t OFF_ES   = OFF_CUR + N_NODES;                        // int[E] src | type<<16
constexpr size_t OFF_DEG  = OFF_ES + N_EDGES;                         // float[N] 1/deg
constexpr size_t OFF_SC   = OFF_DEG + N_NODES;                        // float[N] scale
constexpr size_t OFF_INV  = OFF_SC + N_NODES;                         // float[N] 1/max(scale,.01)
constexpr size_t OFF_BS   = OFF_INV + N_NODES;                        // int[128] block sums
constexpr size_t OFF_BL   = OFF_BS + 128;                             // float[128] block log sums
constexpr size_t OFF_BO   = OFF_BL + 128;                             // int[128] block offsets
constexpr size_t OFF_MEAN = OFF_BO + 128;                             // float[16]
constexpr size_t OFF_REL  = OFF_MEAN + 16;                            // float[L*R*D*B] [l][ty][d][b]
constexpr size_t OFF_PW   = OFF_REL + (size_t)LL * RR * BB * DD;      // float[L*8*1664]
constexpr size_t OFF_F    = OFF_PW + (size_t)LL * 8 * 1664;           // float4[NCHUNKS*32*64] = 41 MB

// ---------------- prep kernels ----------------

__global__ void k_init(const int* __restrict__ h_index, const int* __restrict__ r_index,
                       const float* __restrict__ query_emb, float* __restrict__ x0,
                       int* __restrict__ cursor) {
    int i = blockIdx.x * blockDim.x + threadIdx.x;
    int stride = gridDim.x * blockDim.x;
    for (int t = i; t < N_NODES; t += stride) cursor[t] = 0;
    for (int t = i; t < BB * N_NODES * DD; t += stride) {
        int b = t & 3; int d = (t >> 2) & 31; int n = t >> 7;
        float v = 0.f;
        if (n == h_index[b]) v = query_emb[r_index[b] * DD + d];
        x0[t] = v;
    }
}

__global__ void k_hist(const int* __restrict__ ei, int* __restrict__ cursor) {
    int e = blockIdx.x * blockDim.x + threadIdx.x;
    if (e < N_EDGES) atomicAdd(&cursor[ei[N_EDGES + e]], 1);
}

// per-block partial sums of deg histogram + log(deg)
__global__ void k_part(const int* __restrict__ cursor, int* __restrict__ bsum,
                       float* __restrict__ blog) {
    __shared__ int si[256];
    __shared__ float sf2[256];
    int tid = threadIdx.x;
    int i = blockIdx.x * 256 + tid;
    int v = (i < N_NODES) ? cursor[i] : 0;
    float lg = (i < N_NODES) ? logf((float)(v + 1)) : 0.f;
    si[tid] = v; sf2[tid] = lg;
    __syncthreads();
    for (int off = 128; off > 0; off >>= 1) {
        if (tid < off) { si[tid] += si[tid + off]; sf2[tid] += sf2[tid + off]; }
        __syncthreads();
    }
    if (tid == 0) { bsum[blockIdx.x] = si[0]; blog[blockIdx.x] = sf2[0]; }
}

// single small block: scan the 79 block sums; total log -> mean
__global__ void k_scan2(const int* __restrict__ bsum, const float* __restrict__ blog,
                        int* __restrict__ boff, float* __restrict__ meanw) {
    __shared__ int si[128];
    __shared__ float sf2[128];
    int t = threadIdx.x;
    int v = (t < NBLK) ? bsum[t] : 0;
    float lg = (t < NBLK) ? blog[t] : 0.f;
    si[t] = v; sf2[t] = lg;
    __syncthreads();
    for (int off = 1; off < 128; off <<= 1) {
        int tv = (t >= off) ? si[t - off] : 0;
        float tf = (t >= off) ? sf2[t - off] : 0.f;
        __syncthreads();
        si[t] += tv; sf2[t] += tf;
        __syncthreads();
    }
    if (t < NBLK) boff[t] = si[t] - v;                      // exclusive
    if (t == 127) meanw[0] = sf2[127] / (float)N_NODES;     // mean(log deg)
}

// per-block scan + global offset -> row_ptr/cursor; rdeg/scale/inv
__global__ void k_final(int* __restrict__ cursor, int* __restrict__ row_ptr,
                        const int* __restrict__ boff, const float* __restrict__ meanw,
                        float* __restrict__ rdeg, float* __restrict__ scale,
                        float* __restrict__ invs) {
    __shared__ int si[256];
    int tid = threadIdx.x;
    int i = blockIdx.x * 256 + tid;
    int v = (i < N_NODES) ? cursor[i] : 0;
    si[tid] = v;
    __syncthreads();
    for (int off = 1; off < 256; off <<= 1) {
        int tv = (tid >= off) ? si[tid - off] : 0;
        __syncthreads();
        si[tid] += tv;
        __syncthreads();
    }
    int rp = boff[blockIdx.x] + si[tid] - v;   // exclusive prefix
    if (i < N_NODES) {
        row_ptr[i] = rp;
        cursor[i] = rp;
        float dg = (float)(v + 1);
        float sc = logf(dg) / meanw[0];
        rdeg[i] = 1.f / dg;
        scale[i] = sc;
        invs[i] = 1.f / fmaxf(sc, 0.01f);
    }
    if (i == 0) row_ptr[N_NODES] = N_EDGES;
}

__global__ void k_scatter(const int* __restrict__ ei, const int* __restrict__ et,
                          int* __restrict__ cursor, int* __restrict__ es) {
    int e = blockIdx.x * blockDim.x + threadIdx.x;
    if (e < N_EDGES) {
        int dnode = ei[N_EDGES + e];
        int p = atomicAdd(&cursor[dnode], 1);
        es[p] = ei[e] | (et[e] << 16);
    }
}

// rel tables [l][ty][d][b] + prepped conv weights.
// pw layout per (l, w) with w in [0,8) covering outputs [w*4, w*4+4):
//   [32 quads: x-part, quad j  -> W[o=w*4+0..3][j]]
//   [384 quads: feats, quad jj*12 + f*3 + k -> W[o][32 + (jj*4+f)*3 + k]]
__global__ void k_prep_w(const float* __restrict__ query_emb, const int* __restrict__ r_index,
                         const float* __restrict__ rel_W, const float* __restrict__ rel_b,
                         const float* __restrict__ conv_W,
                         float* __restrict__ rel_all, float* __restrict__ pw) {
    int i = blockIdx.x * blockDim.x + threadIdx.x;
    const int NREL = LL * BB * RR * DD;
    if (i < NREL) {
        int d = i & 31;
        int ty = (i >> 5) % RR;
        int b = (i / (32 * RR)) & 3;
        int l = i / (32 * RR * BB);
        const float* q = query_emb + r_index[b] * DD;
        const float* w = rel_W + ((size_t)l * RR * DD + ty * DD + d) * DD;
        float acc = rel_b[l * RR * DD + ty * DD + d];
        #pragma unroll
        for (int k2 = 0; k2 < DD; ++k2) acc = fmaf(q[k2], w[k2], acc);
        rel_all[(((size_t)l * RR + ty) * DD + d) * BB + b] = acc;
    } else {
        int i2 = i - NREL;
        if (i2 >= LL * 8 * 1664) return;
        int r = i2 % 1664; int lw = i2 / 1664;
        int w = lw & 7, l = lw >> 3;
        int o = w * 4, j;
        if (r < 128) { j = r >> 2; o += (r & 3); }
        else {
            int r2 = r - 128;
            int q2 = r2 >> 2; o += (r2 & 3);
            int jj = q2 / 12, rem = q2 % 12;
            int f = rem / 3, k2 = rem % 3;
            j = DD + (jj * 4 + f) * 3 + k2;
        }
        pw[i2] = conv_W[(size_t)(l * DD + o) * (13 * DD) + j];
    }
}

// ---------------- gather + PNA kernel ----------------
// Wave per node (grid-stride). lane = d + 32*par; parity halves process alternate
// edges (4-deep unroll = 8 x-row dwordx4 loads in flight per wave); shfl_xor(32) combine.
// Writes F transposed: Fq[(chunk*32 + d)*64 + task] = {mean,max,min,std}.
__launch_bounds__(256, 6)
__global__ void k_gather(const float* __restrict__ xin, float4* __restrict__ Fq,
                         const int* __restrict__ row_ptr, const int* __restrict__ es,
                         const float* __restrict__ rel_l, const float* __restrict__ rdeg,
                         const int* __restrict__ h_index, const int* __restrict__ r_index,
                         const float* __restrict__ query_emb) {
    __shared__ __align__(16) float s_rel[RR * BB * DD];   // 18432 B, [ty][d][b]
    const int tid = threadIdx.x;
    {   // stage rel table once per block
        const float4* p4 = (const float4*)rel_l;
        float4* s4 = (float4*)s_rel;
        for (int i = tid; i < RR * BB * DD / 4; i += 256) s4[i] = p4[i];
    }
    const int lane = tid & 63;
    const int d = lane & 31;
    const int par = lane >> 5;
    int hb[4]; float qv[4];
    #pragma unroll
    for (int b = 0; b < 4; ++b) {
        hb[b] = h_index[b];
        qv[b] = query_emb[r_index[b] * DD + d];
    }
    __syncthreads();

    const int nwaves = gridDim.x * 4;
    for (int n = blockIdx.x * 4 + (tid >> 6); n < N_NODES; n += nwaves) {
        float sa[4], sq[4], mx[4], mn[4];
        #pragma unroll
        for (int b = 0; b < 4; ++b) {
            float bv = (n == hb[b]) ? qv[b] : 0.f;
            float bs = par ? 0.f : bv;        // count boundary message once in sum/sq
            sa[b] = bs; sq[b] = bs * bv; mx[b] = bv; mn[b] = bv;
        }
        auto proc = [&](int ee) {
            int pk = es[ee];
            float4 xv = *(const float4*)(xin + ((size_t)(pk & 0xFFFF) * DD + d) * 4);
            float4 rv = *(const float4*)(s_rel + (((pk >> 16) * DD) + d) * 4);
            #pragma unroll
            for (int b = 0; b < 4; ++b) {
                float m = (&xv.x)[b] * (&rv.x)[b];
                sa[b] += m; sq[b] = fmaf(m, m, sq[b]);
                mx[b] = fmaxf(mx[b], m); mn[b] = fminf(mn[b], m);
            }
        };
        int e0 = row_ptr[n], e1 = row_ptr[n + 1];
        int e = e0 + par;                        // parity-strided: 2 edges per step
        for (; e + 6 < e1; e += 8) { proc(e); proc(e + 2); proc(e + 4); proc(e + 6); }
        for (; e < e1; e += 2) proc(e);
        #pragma unroll
        for (int b = 0; b < 4; ++b) {
            sa[b] += __shfl_xor(sa[b], 32);
            sq[b] += __shfl_xor(sq[b], 32);
            mx[b] = fmaxf(mx[b], __shfl_xor(mx[b], 32));
            mn[b] = fminf(mn[b], __shfl_xor(mn[b], 32));
        }
        float rd_ = rdeg[n];
        float mean[4], sd[4];
        #pragma unroll
        for (int b = 0; b < 4; ++b) {
            mean[b] = sa[b] * rd_;
            float sm = sq[b] * rd_;
            sd[b] = sqrtf(fmaxf(sm - mean[b] * mean[b], 1e-6f));
        }
        const int chunk = n >> 4, nl = n & 15;
        int tA = nl * 4 + par * 2;               // each half writes 2 tasks
        float4 fA, fB;
        fA.x = par ? mean[2] : mean[0]; fA.y = par ? mx[2] : mx[0];
        fA.z = par ? mn[2] : mn[0];     fA.w = par ? sd[2] : sd[0];
        fB.x = par ? mean[3] : mean[1]; fB.y = par ? mx[3] : mx[1];
        fB.z = par ? mn[3] : mn[1];     fB.w = par ? sd[3] : sd[1];
        Fq[(size_t)(chunk * 32 + d) * 64 + tA] = fA;
        Fq[(size_t)(chunk * 32 + d) * 64 + tA + 1] = fB;
    }
}

// ---------------- conv kernel ----------------
// Grid 250 x 512 (8 waves = 2 waves/SIMD: the r5 fix — occupancy was 1 wave/SIMD).
// Block owns 5 chunks (T=5). Wave w computes outputs [w*4, w*4+4); lane = task.
// Weights in LDS (53 KB, staged once); per-CU LDS quad traffic unchanged vs r5
// (8 waves x 416 quads = 3328), but now 2 waves/SIMD hide Fq/LDS latency.
__launch_bounds__(512, 2)
__global__ void k_conv(const float* __restrict__ xin, float* __restrict__ xout,
                       const float4* __restrict__ Fq, const float* __restrict__ pw_l,
                       const float* __restrict__ scale, const float* __restrict__ invs,
                       const float* __restrict__ conv_b_l) {
    __shared__ __align__(16) float4 s_pw[8 * 416];   // 53248 B
    const int tid = threadIdx.x;
    {
        const float4* p4 = (const float4*)pw_l;
        for (int i = tid; i < 8 * 416; i += 512) s_pw[i] = p4[i];
    }
    const int wq = __builtin_amdgcn_readfirstlane(tid >> 6);   // 0..7
    const int lane = tid & 63;
    const float4* wx = s_pw + wq * 416;       // x-part: 32 quads (quad j = 4 outputs)
    const float4* wf = wx + 32;               // feats: per jj: 12 quads (f*3+k)
    float bias[4];
    #pragma unroll
    for (int oo = 0; oo < 4; ++oo) bias[oo] = conv_b_l[wq * 4 + oo];
    __syncthreads();

    const int set = blockIdx.x;               // chunks set*5 .. set*5+4
    const int nl2 = lane >> 2, b2 = lane & 3;

    float y[5][3][4];
    #pragma unroll
    for (int cc = 0; cc < 5; ++cc)
        #pragma unroll
        for (int oo = 0; oo < 4; ++oo) {
            y[cc][0][oo] = bias[oo]; y[cc][1][oo] = 0.f; y[cc][2][oo] = 0.f;
        }

    // ---- x part: K rows 0..31 ([n][d][b] layout -> strided dword loads, L2-hot) ----
    #pragma unroll 2
    for (int jj = 0; jj < 8; ++jj) {
        float cxv[5][4];
        #pragma unroll
        for (int cc = 0; cc < 5; ++cc) {
            int n = (set * 5 + cc) * 16 + nl2;
            const float* xb = xin + (size_t)n * 128 + b2;
            #pragma unroll
            for (int dj = 0; dj < 4; ++dj)
                cxv[cc][dj] = xb[(jj * 4 + dj) * 4];
        }
        #pragma unroll
        for (int dj = 0; dj < 4; ++dj) {
            float4 wA = wx[jj * 4 + dj];
            #pragma unroll
            for (int cc = 0; cc < 5; ++cc) {
                float cv = cxv[cc][dj];
                y[cc][0][0] = fmaf(cv, wA.x, y[cc][0][0]);
                y[cc][0][1] = fmaf(cv, wA.y, y[cc][0][1]);
                y[cc][0][2] = fmaf(cv, wA.z, y[cc][0][2]);
                y[cc][0][3] = fmaf(cv, wA.w, y[cc][0][3]);
            }
        }
    }

    // ---- feats: 32 d-blocks, f = mean/max/min/std, k = 1/scale/inv ----
    for (int jj = 0; jj < 32; ++jj) {
        float4 cf[5];
        #pragma unroll
        for (int cc = 0; cc < 5; ++cc)
            cf[cc] = Fq[(size_t)((set * 5 + cc) * 32 + jj) * 64 + lane];
        const float4* wp = wf + jj * 12;
        #pragma unroll
        for (int f = 0; f < 4; ++f) {
            float4 w0 = wp[f * 3], w1 = wp[f * 3 + 1], w2 = wp[f * 3 + 2];
            #pragma unroll
            for (int cc = 0; cc < 5; ++cc) {
                float cv = (&cf[cc].x)[f];
                y[cc][0][0] = fmaf(cv, w0.x, y[cc][0][0]);
                y[cc][0][1] = fmaf(cv, w0.y, y[cc][0][1]);
                y[cc][0][2] = fmaf(cv, w0.z, y[cc][0][2]);
                y[cc][0][3] = fmaf(cv, w0.w, y[cc][0][3]);
                y[cc][1][0] = fmaf(cv, w1.x, y[cc][1][0]);
                y[cc][1][1] = fmaf(cv, w1.y, y[cc][1][1]);
                y[cc][1][2] = fmaf(cv, w1.z, y[cc][1][2]);
                y[cc][1][3] = fmaf(cv, w1.w, y[cc][1][3]);
                y[cc][2][0] = fmaf(cv, w2.x, y[cc][2][0]);
                y[cc][2][1] = fmaf(cv, w2.y, y[cc][2][1]);
                y[cc][2][2] = fmaf(cv, w2.z, y[cc][2][2]);
                y[cc][2][3] = fmaf(cv, w2.w, y[cc][2][3]);
            }
        }
    }

    // ---- epilogue: out[n][o][b] scalar stores ----
    #pragma unroll
    for (int cc = 0; cc < 5; ++cc) {
        int n = (set * 5 + cc) * 16 + nl2;
        float scn = scale[n], ivn = invs[n];
        float* xo = xout + (size_t)n * 128 + b2;
        #pragma unroll
        for (int oo = 0; oo < 4; ++oo) {
            float v = fmaxf(0.f, y[cc][0][oo] + scn * y[cc][1][oo] + ivn * y[cc][2][oo]);
            xo[(wq * 4 + oo) * 4] = v;
        }
    }
}

// ---------------- final scoring ----------------
__global__ void k_score(const float* __restrict__ xL, const float* __restrict__ query_emb,
                        const int* __restrict__ r_index, const int* __restrict__ t_index,
                        const float* __restrict__ W1, const float* __restrict__ b1,
                        const float* __restrict__ W2, const float* __restrict__ b2,
                        float* __restrict__ out) {
    int bi = blockIdx.x;            // 0..127
    int b = bi >> 5, kk = bi & 31;
    int j = threadIdx.x;            // 0..63
    __shared__ float sf[64];
    int t = t_index[b * KK + kk];
    float f = (j < DD) ? xL[(size_t)t * 128 + j * 4 + b]
                       : query_emb[r_index[b] * DD + (j - DD)];
    sf[j] = f;
    __syncthreads();
    float acc = b1[j];
    #pragma unroll 8
    for (int i2 = 0; i2 < 64; ++i2) acc = fmaf(sf[i2], W1[j * 64 + i2], acc);
    float h = fmaxf(acc, 0.f);
    float prod = h * W2[j];
    #pragma unroll
    for (int off = 32; off > 0; off >>= 1) prod += __shfl_down(prod, off);
    if (j == 0) out[b * KK + kk] = prod + b2[0];
}

extern "C" void kernel_launch(void* const* d_in, const int* in_sizes, int n_in,
                              void* d_out, int out_size, void* d_ws, size_t ws_size,
                              hipStream_t stream) {
    const int* ei        = (const int*)d_in[0];
    const int* et        = (const int*)d_in[1];
    const int* h_index   = (const int*)d_in[2];
    const int* t_index   = (const int*)d_in[3];
    const int* r_index   = (const int*)d_in[4];
    const float* query_emb = (const float*)d_in[6];
    const float* rel_W   = (const float*)d_in[7];
    const float* rel_b   = (const float*)d_in[8];
    const float* conv_W  = (const float*)d_in[9];
    const float* conv_b  = (const float*)d_in[10];
    const float* W1      = (const float*)d_in[11];
    const float* b1      = (const float*)d_in[12];
    const float* W2      = (const float*)d_in[13];
    const float* b2      = (const float*)d_in[14];

    float* ws = (float*)d_ws;
    float* x0      = ws + OFF_X0;
    float* x1      = ws + OFF_X1;
    int*   row_ptr = (int*)(ws + OFF_RP);
    int*   cursor  = (int*)(ws + OFF_CUR);
    int*   es      = (int*)(ws + OFF_ES);
    float* rdeg    = ws + OFF_DEG;
    float* sc      = ws + OFF_SC;
    float* invs    = ws + OFF_INV;
    int*   bsum    = (int*)(ws + OFF_BS);
    float* blog    = ws + OFF_BL;
    int*   boff    = (int*)(ws + OFF_BO);
    float* meanw   = ws + OFF_MEAN;
    float* rel_all = ws + OFF_REL;
    float* pw      = ws + OFF_PW;
    float4* Fq     = (float4*)(ws + OFF_F);
    float* out     = (float*)d_out;

    // prep
    k_init<<<1024, 256, 0, stream>>>(h_index, r_index, query_emb, x0, cursor);
    k_hist<<<(N_EDGES + 255) / 256, 256, 0, stream>>>(ei, cursor);
    k_part<<<NBLK, 256, 0, stream>>>(cursor, bsum, blog);
    k_scan2<<<1, 128, 0, stream>>>(bsum, blog, boff, meanw);
    k_final<<<NBLK, 256, 0, stream>>>(cursor, row_ptr, boff, meanw, rdeg, sc, invs);
    k_scatter<<<(N_EDGES + 255) / 256, 256, 0, stream>>>(ei, et, cursor, es);
    const int NPREP = LL * BB * RR * DD + LL * 8 * 1664;
    k_prep_w<<<(NPREP + 255) / 256, 256, 0, stream>>>(query_emb, r_index, rel_W, rel_b,
                                                      conv_W, rel_all, pw);

    // 4 BF layers, ping-pong x0/x1
    for (int l = 0; l < LL; ++l) {
        const float* xi = (l & 1) ? x1 : x0;
        float* xo = (l & 1) ? x0 : x1;
        k_gather<<<1536, 256, 0, stream>>>(xi, Fq, row_ptr, es,
                                           rel_all + (size_t)l * RR * BB * DD,
                                           rdeg, h_index, r_index, query_emb);
        k_conv<<<250, 512, 0, stream>>>(xi, xo, Fq, pw + (size_t)l * 8 * 1664,
                                        sc, invs, conv_b + l * DD);
    }

    k_score<<<BB * KK, 64, 0, stream>>>(x0, query_emb, r_index, t_index, W1, b1, W2, b2, out);
}